// Round 7
// baseline (887.172 us; speedup 1.0000x reference)
//
#include <hip/hip_runtime.h>
#include <math.h>

// Problem constants (B=2, H=8, S=2048, D=64)
#define BH_    16
#define S_     2048
#define D_     64
#define KELEMS (BH_ * S_ * D_)       // 2,097,152 K elements
#define NROWS  (BH_ * S_)            // 32,768 query rows

// ---- two-phase path geometry
#define SUPC   256      // support cap/row in phase B (R5 passed with 256 total
                        // candidates/row, support <= candidates)
#define QT_A   16       // queries per phase-A block (MFMA M)
#define KTW_A  8        // 16-key tiles per wave (128 keys/wave, 4 waves)
#define ITW_A  8        // wave-subset Newton iterations (early-exit)
#define BMAXIT 32       // phase-B Newton max iterations

// ---- fallback (R5 single-kernel) geometry
#define QT_F    32
#define BLOCK_F 1024
#define NW_F    16
#define KTW_F   8
#define CAP_F   256
#define ITPRE_F 5
#define WMAXIT_F 16

typedef __attribute__((ext_vector_type(8))) short bf16x8;   // 8 bf16 = 4 VGPR
typedef __attribute__((ext_vector_type(4))) float f32x4;

// Exact hi/lo bf16 truncation split of 8 consecutive floats.
// x = hi + lo + eps, |eps| <= 2^-15 |x|; products use hh + hl + lh (drop ll).
__device__ __forceinline__ void split8(const float4 f0, const float4 f1,
                                       bf16x8& hi, bf16x8& lo) {
  union { bf16x8 v; unsigned int u[4]; } H, L;
  const float ff[8] = {f0.x, f0.y, f0.z, f0.w, f1.x, f1.y, f1.z, f1.w};
#pragma unroll
  for (int p = 0; p < 4; ++p) {
    unsigned int b0 = __float_as_uint(ff[2 * p]);
    unsigned int b1 = __float_as_uint(ff[2 * p + 1]);
    unsigned int h0 = b0 & 0xFFFF0000u;
    unsigned int h1 = b1 & 0xFFFF0000u;
    H.u[p] = (h0 >> 16) | h1;                       // lo short = elem 2p
    float l0 = ff[2 * p]     - __uint_as_float(h0); // exact in fp32
    float l1 = ff[2 * p + 1] - __uint_as_float(h1);
    L.u[p] = (__float_as_uint(l0) >> 16) | (__float_as_uint(l1) & 0xFFFF0000u);
  }
  hi = H.v; lo = L.v;
}

// Prepass: K fp32 -> (Khi, Klo) bf16 (same element order). Also zeroes the
// per-row global candidate counters (two-phase path only).
__global__ __launch_bounds__(256)
void ksplit_kernel(const float* __restrict__ k,
                   unsigned short* __restrict__ khi,
                   unsigned short* __restrict__ klo,
                   int* __restrict__ gcnt) {
  const int gi = blockIdx.x * 256 + threadIdx.x;
  if (gcnt != nullptr && gi < NROWS) gcnt[gi] = 0;
  const int i = gi * 4;
  float4 x = *(const float4*)(k + i);
  ushort4 h, l;
  {
    unsigned int b;
    b = __float_as_uint(x.x); h.x = (unsigned short)(b >> 16);
    l.x = (unsigned short)(__float_as_uint(x.x - __uint_as_float(b & 0xFFFF0000u)) >> 16);
    b = __float_as_uint(x.y); h.y = (unsigned short)(b >> 16);
    l.y = (unsigned short)(__float_as_uint(x.y - __uint_as_float(b & 0xFFFF0000u)) >> 16);
    b = __float_as_uint(x.z); h.z = (unsigned short)(b >> 16);
    l.z = (unsigned short)(__float_as_uint(x.z - __uint_as_float(b & 0xFFFF0000u)) >> 16);
    b = __float_as_uint(x.w); h.w = (unsigned short)(b >> 16);
    l.w = (unsigned short)(__float_as_uint(x.w - __uint_as_float(b & 0xFFFF0000u)) >> 16);
  }
  *(ushort4*)(khi + i) = h;
  *(ushort4*)(klo + i) = l;
}

// ============ Phase A: MFMA scores + wave-local compaction ============
// Block = 16 q x 512 keys; each of 4 waves owns 128 keys. A wave runs Newton
// on ITS OWN 128-key subset from below: every iterate tau_w <= subset root
// <= tau* (subset sum <= full sum; f decreasing), so admitting {x > tau_w}
// keeps the full support for ANY data. Overflow past capg is only COUNTED
// (phase B repairs those rows exactly). No barriers, no LDS.
__global__ __launch_bounds__(256, 5)   // ~102 VGPR budget -> 5 waves/SIMD
void entmax_scores_kernel(const float* __restrict__ q,
                          const unsigned short* __restrict__ khi,
                          const unsigned short* __restrict__ klo,
                          int* __restrict__ gcnt,
                          int2* __restrict__ gent,
                          const int capg) {
  const int t    = threadIdx.x;
  const int wave = t >> 6;
  const int lane = t & 63;
  const int g    = lane >> 4;
  const int col  = lane & 15;

  // head-XCD affinity: bh = blk & 15 -> blk % 8 == bh % 8 under round-robin.
  const int blk  = blockIdx.x;
  const int bh   = blk & 15;
  const int kseg = (blk >> 4) & 3;
  const int qt   = blk >> 6;                   // 0..127
  const float* qp = q + ((size_t)bh * S_ + (size_t)qt * QT_A) * D_;

  // Q fragment: A row = col, d = ks*32 + g*8 + i; fold scale/2 => *1/16.
  bf16x8 qh[2], ql[2];
#pragma unroll
  for (int ks = 0; ks < 2; ++ks) {
    const float* src = qp + col * D_ + ks * 32 + g * 8;
    float4 f0 = *(const float4*)src;
    float4 f1 = *(const float4*)(src + 4);
    f0.x *= 0.0625f; f0.y *= 0.0625f; f0.z *= 0.0625f; f0.w *= 0.0625f;
    f1.x *= 0.0625f; f1.y *= 0.0625f; f1.z *= 0.0625f; f1.w *= 0.0625f;
    split8(f0, f1, qh[ks], ql[ks]);
  }

  // QK^T over this wave's 128 keys: acc[kt][j] = x[row=g*4+j][kbase+kt*16+col]
  const int kbase = kseg * 512 + wave * 128;
  f32x4 acc[KTW_A];
#pragma unroll
  for (int kt = 0; kt < KTW_A; ++kt) acc[kt] = (f32x4){0.f, 0.f, 0.f, 0.f};
#pragma unroll
  for (int kt = 0; kt < KTW_A; ++kt) {
    const size_t rowoff = ((size_t)bh * S_ + kbase + kt * 16 + col) * D_;
#pragma unroll
    for (int ks = 0; ks < 2; ++ks) {
      bf16x8 kh = *(const bf16x8*)(khi + rowoff + ks * 32 + g * 8);
      bf16x8 kl = *(const bf16x8*)(klo + rowoff + ks * 32 + g * 8);
      acc[kt] = __builtin_amdgcn_mfma_f32_16x16x32_bf16(qh[ks], kh, acc[kt], 0, 0, 0);
      acc[kt] = __builtin_amdgcn_mfma_f32_16x16x32_bf16(qh[ks], kl, acc[kt], 0, 0, 0);
      acc[kt] = __builtin_amdgcn_mfma_f32_16x16x32_bf16(ql[ks], kh, acc[kt], 0, 0, 0);
    }
  }

  // Wave-local row max over its 128 keys (16-lane col-group butterfly).
  float m4[4];
#pragma unroll
  for (int j = 0; j < 4; ++j) {
    float mm = acc[0][j];
#pragma unroll
    for (int kt = 1; kt < KTW_A; ++kt) mm = fmaxf(mm, acc[kt][j]);
    m4[j] = mm;
  }
#pragma unroll
  for (int off = 1; off < 16; off <<= 1)
#pragma unroll
    for (int j = 0; j < 4; ++j) m4[j] = fmaxf(m4[j], __shfl_xor(m4[j], off, 64));

  // Wave-subset Newton from tau0 = m_w - 1 (f_w(tau0) >= 0; s1 > 0 below
  // the subset root -> no div-by-0). Early exit when all 4 rows converge.
  float tau[4];
#pragma unroll
  for (int j = 0; j < 4; ++j) tau[j] = m4[j] - 1.0f;
  for (int it = 0; it < ITW_A; ++it) {
    float s1[4] = {0, 0, 0, 0}, s2[4] = {0, 0, 0, 0};
#pragma unroll
    for (int kt = 0; kt < KTW_A; ++kt)
#pragma unroll
      for (int j = 0; j < 4; ++j) {
        float u = fmaxf(acc[kt][j] - tau[j], 0.f);
        s1[j] += u; s2[j] = fmaf(u, u, s2[j]);
      }
#pragma unroll
    for (int off = 1; off < 16; off <<= 1)
#pragma unroll
      for (int j = 0; j < 4; ++j) {
        s1[j] += __shfl_xor(s1[j], off, 64);
        s2[j] += __shfl_xor(s2[j], off, 64);
      }
    float ms = 0.f;
#pragma unroll
    for (int j = 0; j < 4; ++j) {
      float st = (s2[j] - 1.0f) / (2.0f * s1[j]);
      tau[j] += st;
      ms = fmaxf(ms, st);
    }
    if (__ballot(ms >= 1e-7f) == 0ull) break;    // wave-uniform exit
  }

  // Compact {x > tau_w} to the global per-row lists (count-only past capg).
#pragma unroll
  for (int kt = 0; kt < KTW_A; ++kt)
#pragma unroll
    for (int j = 0; j < 4; ++j) {
      float x = acc[kt][j];
      if (x > tau[j]) {
        const int rowg = bh * S_ + qt * QT_A + g * 4 + j;
        int slot = atomicAdd(&gcnt[rowg], 1);
        if (slot < capg)
          gent[(size_t)rowg * capg + slot] =
              make_int2(kbase + kt * 16 + col, __float_as_int(x));
      }
    }
}

// ============ Phase B: exact per-row Newton + sparse PV ============
// One wave per row (4 rows / 256-thread block). Normal path: Newton on the
// <= capg candidates in registers. Overflow path (gcnt > capg, rare by
// construction, correct for ANY data): recompute the whole row in fp32 and
// solve exactly. Support (p>0) -> LDS -> PV over ~20-35 keys. No barriers
// (all LDS state is wave-private; same-wave LDS ops are in-order).
template <int NR>
__global__ __launch_bounds__(256)
void entmax_solvepv_kernel(const float* __restrict__ q,
                           const float* __restrict__ k,
                           const float* __restrict__ v,
                           const int* __restrict__ gcnt,
                           const int2* __restrict__ gent,
                           const int capg,
                           float* __restrict__ out) {
  __shared__ int   sidx[4][SUPC];
  __shared__ float sp[4][SUPC];
  __shared__ unsigned int scnt[4];
  __shared__ float qs[4][D_];

  const int t    = threadIdx.x;
  const int wid  = t >> 6;
  const int lane = t & 63;
  const int blk  = blockIdx.x;
  const int bh   = blk & 15;                   // head-XCD affinity for V
  const int u    = blk >> 4;                   // 0..511
  const int rowg = bh * S_ + u * 4 + wid;
  const float* vp = v + (size_t)bh * S_ * D_;

  if (lane == 0) scnt[wid] = 0;

  const int n = gcnt[rowg];
  if (n <= capg) {
    const int2* ge = gent + (size_t)rowg * capg;
    float xv[NR]; int iv[NR];
#pragma unroll
    for (int r = 0; r < NR; ++r) {
      const int i = lane + (r << 6);
      int2 e = (i < n) ? ge[i] : make_int2(0, __float_as_int(-1e30f));
      iv[r] = e.x; xv[r] = __int_as_float(e.y);
    }
    float mx = xv[0];
#pragma unroll
    for (int r = 1; r < NR; ++r) mx = fmaxf(mx, xv[r]);
#pragma unroll
    for (int off = 1; off < 64; off <<= 1) mx = fmaxf(mx, __shfl_xor(mx, off, 64));
    float tau = mx - 1.0f;    // row max is always a candidate (x_max > tau_w)
    for (int it = 0; it < BMAXIT; ++it) {
      float s1 = 0.f, s2 = 0.f;
#pragma unroll
      for (int r = 0; r < NR; ++r) {
        float uu = fmaxf(xv[r] - tau, 0.f);
        s1 += uu; s2 = fmaf(uu, uu, s2);
      }
#pragma unroll
      for (int off = 1; off < 64; off <<= 1) {
        s1 += __shfl_xor(s1, off, 64);
        s2 += __shfl_xor(s2, off, 64);
      }
      float step = (s2 - 1.0f) / (2.0f * s1);
      tau += step;
      if (step < 1e-7f) break;                  // lane-uniform
    }
#pragma unroll
    for (int r = 0; r < NR; ++r) {
      const int i = lane + (r << 6);
      if (i < n) {
        float uu = xv[r] - tau;
        if (uu > 0.f) {
          unsigned int slot = atomicAdd(&scnt[wid], 1u);
          if (slot < SUPC) { sidx[wid][slot] = iv[r]; sp[wid][slot] = uu * uu; }
        }
      }
    }
  } else {
    // ---- overflow repair: exact fp32 recompute of this row (32 keys/lane).
    qs[wid][lane] = q[(size_t)rowg * D_ + lane] * 0.0625f;
    const float* kb = k + (size_t)bh * S_ * D_;
    float xs[32];
    for (int r = 0; r < 32; ++r) {
      const float* krow = kb + (size_t)(lane + (r << 6)) * D_;
      float d = 0.f;
#pragma unroll 4
      for (int dc = 0; dc < D_; dc += 4) {
        float4 kv4 = *(const float4*)(krow + dc);
        d = fmaf(qs[wid][dc + 0], kv4.x, d);
        d = fmaf(qs[wid][dc + 1], kv4.y, d);
        d = fmaf(qs[wid][dc + 2], kv4.z, d);
        d = fmaf(qs[wid][dc + 3], kv4.w, d);
      }
      xs[r] = d;
    }
    float mx = xs[0];
#pragma unroll
    for (int r = 1; r < 32; ++r) mx = fmaxf(mx, xs[r]);
#pragma unroll
    for (int off = 1; off < 64; off <<= 1) mx = fmaxf(mx, __shfl_xor(mx, off, 64));
    float tau = mx - 1.0f;
    for (int it = 0; it < BMAXIT; ++it) {
      float s1 = 0.f, s2 = 0.f;
#pragma unroll
      for (int r = 0; r < 32; ++r) {
        float uu = fmaxf(xs[r] - tau, 0.f);
        s1 += uu; s2 = fmaf(uu, uu, s2);
      }
#pragma unroll
      for (int off = 1; off < 64; off <<= 1) {
        s1 += __shfl_xor(s1, off, 64);
        s2 += __shfl_xor(s2, off, 64);
      }
      float step = (s2 - 1.0f) / (2.0f * s1);
      tau += step;
      if (step < 1e-7f) break;
    }
#pragma unroll
    for (int r = 0; r < 32; ++r) {
      float uu = xs[r] - tau;
      if (uu > 0.f) {
        unsigned int slot = atomicAdd(&scnt[wid], 1u);
        if (slot < SUPC) { sidx[wid][slot] = lane + (r << 6); sp[wid][slot] = uu * uu; }
      }
    }
  }

  int sn = (int)scnt[wid]; if (sn > SUPC) sn = SUPC;
  float s = 0.f;
#pragma unroll 4
  for (int i = 0; i < sn; ++i)
    s = fmaf(sp[wid][i], vp[(size_t)sidx[wid][i] * D_ + lane], s);
  out[(size_t)rowg * D_ + lane] = s;
}

// ============ Fallback: R5 single-kernel path (verbatim) ============
template <bool PRE>
__global__ __launch_bounds__(BLOCK_F, 4)
void entmax_attn_kernel(const float* __restrict__ q,
                        const float* __restrict__ k,
                        const unsigned short* __restrict__ khi,
                        const unsigned short* __restrict__ klo,
                        const float* __restrict__ v,
                        float* __restrict__ out) {
  __shared__ float redM[NW_F][QT_F];
  __shared__ float redS1[2][NW_F][QT_F];
  __shared__ float redS2[2][NW_F][QT_F];
  __shared__ unsigned int cnt[QT_F];
  __shared__ int   lidx[QT_F][CAP_F];
  __shared__ float lval[QT_F][CAP_F];

  const int t    = threadIdx.x;
  const int wid  = t >> 6;
  const int lane = t & 63;
  const int g    = lane >> 4;
  const int col  = lane & 15;
  const int rowL = lane & 31;

  const int blk = blockIdx.x;
  const int bh  = blk & 15;
  const int qt  = blk >> 4;
  const float* qp = q + ((size_t)bh * S_ + (size_t)qt * QT_F) * D_;
  const float* kp = k + (size_t)bh * S_ * D_;
  const float* vp = v + (size_t)bh * S_ * D_;
  float* op = out + ((size_t)bh * S_ + (size_t)qt * QT_F) * D_;

  if (t < QT_F) cnt[t] = 0;

  bf16x8 qh[2][2], ql[2][2];
#pragma unroll
  for (int f = 0; f < 2; ++f)
#pragma unroll
    for (int ks = 0; ks < 2; ++ks) {
      const float* src = qp + (f * 16 + col) * D_ + ks * 32 + g * 8;
      float4 f0 = *(const float4*)src;
      float4 f1 = *(const float4*)(src + 4);
      f0.x *= 0.0625f; f0.y *= 0.0625f; f0.z *= 0.0625f; f0.w *= 0.0625f;
      f1.x *= 0.0625f; f1.y *= 0.0625f; f1.z *= 0.0625f; f1.w *= 0.0625f;
      split8(f0, f1, qh[f][ks], ql[f][ks]);
    }

  f32x4 acc[2][KTW_F];
#pragma unroll
  for (int f = 0; f < 2; ++f)
#pragma unroll
    for (int kt = 0; kt < KTW_F; ++kt) acc[f][kt] = (f32x4){0.f, 0.f, 0.f, 0.f};
#pragma unroll
  for (int kt = 0; kt < KTW_F; ++kt) {
    const size_t rowoff = (size_t)(wid * 128 + kt * 16 + col) * D_;
#pragma unroll
    for (int ks = 0; ks < 2; ++ks) {
      bf16x8 kh, kl;
      if (PRE) {
        const size_t eoff = (size_t)bh * S_ * D_ + rowoff + ks * 32 + g * 8;
        kh = *(const bf16x8*)(khi + eoff);
        kl = *(const bf16x8*)(klo + eoff);
      } else {
        const float* src = kp + rowoff + ks * 32 + g * 8;
        split8(*(const float4*)src, *(const float4*)(src + 4), kh, kl);
      }
#pragma unroll
      for (int f = 0; f < 2; ++f) {
        acc[f][kt] = __builtin_amdgcn_mfma_f32_16x16x32_bf16(qh[f][ks], kh, acc[f][kt], 0, 0, 0);
        acc[f][kt] = __builtin_amdgcn_mfma_f32_16x16x32_bf16(qh[f][ks], kl, acc[f][kt], 0, 0, 0);
        acc[f][kt] = __builtin_amdgcn_mfma_f32_16x16x32_bf16(ql[f][ks], kh, acc[f][kt], 0, 0, 0);
      }
    }
  }

  {
    float m4[2][4];
#pragma unroll
    for (int f = 0; f < 2; ++f)
#pragma unroll
      for (int j = 0; j < 4; ++j) {
        float mm = acc[f][0][j];
#pragma unroll
        for (int kt = 1; kt < KTW_F; ++kt) mm = fmaxf(mm, acc[f][kt][j]);
        m4[f][j] = mm;
      }
#pragma unroll
    for (int off = 1; off < 16; off <<= 1)
#pragma unroll
      for (int f = 0; f < 2; ++f)
#pragma unroll
        for (int j = 0; j < 4; ++j)
          m4[f][j] = fmaxf(m4[f][j], __shfl_xor(m4[f][j], off, 64));
    if (col == 0) {
#pragma unroll
      for (int f = 0; f < 2; ++f)
#pragma unroll
        for (int j = 0; j < 4; ++j) redM[wid][f * 16 + g * 4 + j] = m4[f][j];
    }
  }
  __syncthreads();

  float tauRow;
  {
    float mm = redM[0][rowL];
#pragma unroll
    for (int w = 1; w < NW_F; ++w) mm = fmaxf(mm, redM[w][rowL]);
    tauRow = mm - 1.0f;
  }
  float tau[2][4];
#pragma unroll
  for (int f = 0; f < 2; ++f)
#pragma unroll
    for (int j = 0; j < 4; ++j) tau[f][j] = __shfl(tauRow, f * 16 + g * 4 + j);

  for (int it = 0; it < ITPRE_F; ++it) {
    const int b = it & 1;
    float s1[2][4] = {{0,0,0,0},{0,0,0,0}}, s2[2][4] = {{0,0,0,0},{0,0,0,0}};
#pragma unroll
    for (int kt = 0; kt < KTW_F; ++kt)
#pragma unroll
      for (int f = 0; f < 2; ++f)
#pragma unroll
        for (int j = 0; j < 4; ++j) {
          float u = fmaxf(acc[f][kt][j] - tau[f][j], 0.f);
          s1[f][j] += u; s2[f][j] = fmaf(u, u, s2[f][j]);
        }
#pragma unroll
    for (int off = 1; off < 16; off <<= 1)
#pragma unroll
      for (int f = 0; f < 2; ++f)
#pragma unroll
        for (int j = 0; j < 4; ++j) {
          s1[f][j] += __shfl_xor(s1[f][j], off, 64);
          s2[f][j] += __shfl_xor(s2[f][j], off, 64);
        }
    if (col == 0) {
#pragma unroll
      for (int f = 0; f < 2; ++f)
#pragma unroll
        for (int j = 0; j < 4; ++j) {
          redS1[b][wid][f * 16 + g * 4 + j] = s1[f][j];
          redS2[b][wid][f * 16 + g * 4 + j] = s2[f][j];
        }
    }
    __syncthreads();
    const float* pS = (lane < 32) ? &redS1[b][0][rowL] : &redS2[b][0][rowL];
    float T = 0.f;
#pragma unroll
    for (int w = 0; w < NW_F; ++w) T += pS[w * QT_F];
    float other = __shfl_xor(T, 32, 64);
    float step_r = (other - 1.0f) / (2.0f * T);
    if (lane < 32) tauRow += step_r;
#pragma unroll
    for (int f = 0; f < 2; ++f)
#pragma unroll
      for (int j = 0; j < 4; ++j)
        tau[f][j] += __shfl(step_r, f * 16 + g * 4 + j);
  }

#pragma unroll
  for (int kt = 0; kt < KTW_F; ++kt)
#pragma unroll
    for (int f = 0; f < 2; ++f)
#pragma unroll
      for (int j = 0; j < 4; ++j) {
        float x = acc[f][kt][j];
        if (x > tau[f][j]) {
          const int row = f * 16 + g * 4 + j;
          unsigned int s = atomicAdd(&cnt[row], 1u);
          if (s < CAP_F) {
            lidx[row][s] = wid * 128 + kt * 16 + col;
            lval[row][s] = x;
          }
        }
      }
  __syncthreads();

  for (int rr = 0; rr < 2; ++rr) {
    const int row = wid * 2 + rr;
    int n = (int)cnt[row]; if (n > CAP_F) n = CAP_F;
    float xv[4];
#pragma unroll
    for (int r = 0; r < 4; ++r) {
      const int i = lane + 64 * r;
      xv[r] = (i < n) ? lval[row][i] : -1e30f;
    }
    float tw = __shfl(tauRow, row);
    for (int it = 0; it < WMAXIT_F; ++it) {
      float s1 = 0.f, s2 = 0.f;
#pragma unroll
      for (int r = 0; r < 4; ++r) {
        float u = fmaxf(xv[r] - tw, 0.f);
        s1 += u; s2 = fmaf(u, u, s2);
      }
#pragma unroll
      for (int off = 1; off < 64; off <<= 1) {
        s1 += __shfl_xor(s1, off, 64);
        s2 += __shfl_xor(s2, off, 64);
      }
      float step = (s2 - 1.0f) / (2.0f * s1);
      tw += step;
      if (step < 1e-7f) break;
    }
#pragma unroll
    for (int r = 0; r < 4; ++r) {
      const int i = lane + 64 * r;
      if (i < n) {
        float u = fmaxf(xv[r] - tw, 0.f);
        lval[row][i] = u * u;
      }
    }
    float s = 0.f;
#pragma unroll 4
    for (int i = 0; i < n; ++i) {
      s = fmaf(lval[row][i], vp[(size_t)lidx[row][i] * D_ + lane], s);
    }
    op[row * D_ + lane] = s;
  }
}

extern "C" void kernel_launch(void* const* d_in, const int* in_sizes, int n_in,
                              void* d_out, int out_size, void* d_ws, size_t ws_size,
                              hipStream_t stream) {
  const float* q = (const float*)d_in[0];
  const float* k = (const float*)d_in[1];
  const float* v = (const float*)d_in[2];
  float* out = (float*)d_out;

  const size_t khi_b = (size_t)KELEMS * 2;                 // 4 MB
  const size_t cnt_b = (size_t)NROWS * 4;                  // 128 KB
  const size_t base  = 2 * khi_b + cnt_b;                  // ~8.5 MB

  int capg = 0;
  if (d_ws != nullptr) {
    if      (ws_size >= base + (size_t)NROWS * 512 * 8) capg = 512;  // ~143 MB
    else if (ws_size >= base + (size_t)NROWS * 256 * 8) capg = 256;  // ~76 MB
    else if (ws_size >= base + (size_t)NROWS * 128 * 8) capg = 128;  // ~42 MB
  }

  if (capg != 0) {
    unsigned short* khi = (unsigned short*)d_ws;
    unsigned short* klo = khi + KELEMS;
    int*  gcnt = (int*)((char*)d_ws + 2 * khi_b);
    int2* gent = (int2*)((char*)d_ws + base);
    ksplit_kernel<<<dim3(KELEMS / (256 * 4)), dim3(256), 0, stream>>>(k, khi, klo, gcnt);
    entmax_scores_kernel<<<dim3(BH_ * 4 * (S_ / QT_A)), dim3(256), 0, stream>>>(
        q, khi, klo, gcnt, gent, capg);
    const dim3 gB(NROWS / 4);
    if (capg == 512)
      entmax_solvepv_kernel<8><<<gB, dim3(256), 0, stream>>>(q, k, v, gcnt, gent, capg, out);
    else if (capg == 256)
      entmax_solvepv_kernel<4><<<gB, dim3(256), 0, stream>>>(q, k, v, gcnt, gent, capg, out);
    else
      entmax_solvepv_kernel<2><<<gB, dim3(256), 0, stream>>>(q, k, v, gcnt, gent, capg, out);
  } else if (d_ws != nullptr && ws_size >= 2 * khi_b) {
    unsigned short* khi = (unsigned short*)d_ws;
    unsigned short* klo = khi + KELEMS;
    ksplit_kernel<<<dim3(KELEMS / (256 * 4)), dim3(256), 0, stream>>>(k, khi, klo, nullptr);
    entmax_attn_kernel<true><<<dim3(BH_ * (S_ / QT_F)), dim3(BLOCK_F), 0, stream>>>(
        q, k, khi, klo, v, out);
  } else {
    entmax_attn_kernel<false><<<dim3(BH_ * (S_ / QT_F)), dim3(BLOCK_F), 0, stream>>>(
        q, k, nullptr, nullptr, v, out);
  }
}

// Round 8
// 307.714 us; speedup vs baseline: 2.8831x; 2.8831x over previous
//
#include <hip/hip_runtime.h>
#include <math.h>

// Problem constants (B=2, H=8, S=2048, D=64)
#define BH_    16
#define S_     2048
#define D_     64
#define KELEMS (BH_ * S_ * D_)       // 2,097,152 K elements
#define NROWS  (BH_ * S_)            // 32,768 query rows
#define NSEG   16                    // wave-segments per row (4 kseg x 4 waves)

// ---- two-phase path geometry
#define SUPC   256      // support cap/row in phase B (R5 passed with <=256
                        // candidates/row at tighter threshold; support <= that)
#define QT_A   16       // queries per phase-A block (MFMA M)
#define KTW_A  8        // 16-key tiles per wave (128 keys/wave, 4 waves)
#define ITW_A  8        // wave-subset Newton iterations (early-exit)
#define BMAXIT 32       // phase-B Newton max iterations

// ---- fallback (R5 single-kernel) geometry
#define QT_F    32
#define BLOCK_F 1024
#define NW_F    16
#define KTW_F   8
#define CAP_F   256
#define ITPRE_F 5
#define WMAXIT_F 16

typedef __attribute__((ext_vector_type(8))) short bf16x8;   // 8 bf16 = 4 VGPR
typedef __attribute__((ext_vector_type(4))) float f32x4;

// Exact hi/lo bf16 truncation split of 8 consecutive floats.
// x = hi + lo + eps, |eps| <= 2^-15 |x|; products use hh + hl + lh (drop ll).
__device__ __forceinline__ void split8(const float4 f0, const float4 f1,
                                       bf16x8& hi, bf16x8& lo) {
  union { bf16x8 v; unsigned int u[4]; } H, L;
  const float ff[8] = {f0.x, f0.y, f0.z, f0.w, f1.x, f1.y, f1.z, f1.w};
#pragma unroll
  for (int p = 0; p < 4; ++p) {
    unsigned int b0 = __float_as_uint(ff[2 * p]);
    unsigned int b1 = __float_as_uint(ff[2 * p + 1]);
    unsigned int h0 = b0 & 0xFFFF0000u;
    unsigned int h1 = b1 & 0xFFFF0000u;
    H.u[p] = (h0 >> 16) | h1;                       // lo short = elem 2p
    float l0 = ff[2 * p]     - __uint_as_float(h0); // exact in fp32
    float l1 = ff[2 * p + 1] - __uint_as_float(h1);
    L.u[p] = (__float_as_uint(l0) >> 16) | (__float_as_uint(l1) & 0xFFFF0000u);
  }
  hi = H.v; lo = L.v;
}

// Prepass: K fp32 -> (Khi, Klo) bf16 (same element order). No counter zeroing
// needed anymore: phase A writes every per-segment count unconditionally.
__global__ __launch_bounds__(256)
void ksplit_kernel(const float* __restrict__ k,
                   unsigned short* __restrict__ khi,
                   unsigned short* __restrict__ klo) {
  const int i = (blockIdx.x * 256 + threadIdx.x) * 4;
  float4 x = *(const float4*)(k + i);
  ushort4 h, l;
  {
    unsigned int b;
    b = __float_as_uint(x.x); h.x = (unsigned short)(b >> 16);
    l.x = (unsigned short)(__float_as_uint(x.x - __uint_as_float(b & 0xFFFF0000u)) >> 16);
    b = __float_as_uint(x.y); h.y = (unsigned short)(b >> 16);
    l.y = (unsigned short)(__float_as_uint(x.y - __uint_as_float(b & 0xFFFF0000u)) >> 16);
    b = __float_as_uint(x.z); h.z = (unsigned short)(b >> 16);
    l.z = (unsigned short)(__float_as_uint(x.z - __uint_as_float(b & 0xFFFF0000u)) >> 16);
    b = __float_as_uint(x.w); h.w = (unsigned short)(b >> 16);
    l.w = (unsigned short)(__float_as_uint(x.w - __uint_as_float(b & 0xFFFF0000u)) >> 16);
  }
  *(ushort4*)(khi + i) = h;
  *(ushort4*)(klo + i) = l;
}

// ============ Phase A: MFMA scores + ATOMIC-FREE wave compaction ============
// Block = 16 q x 512 keys; wave owns 128 keys (segment seg = kseg*4+wave).
// Wave-subset Newton from below: tau_w <= subset root <= tau*, so admitting
// {x > tau_w} keeps the full support for ANY data. Slot assignment is pure
// ballot+popcount-prefix within the row's 16-lane group (R7 lesson: the
// per-candidate global atomicAdd chain was ~680us of serialized round-trips).
// Entries are 4B: fp32 score with its low 11 mantissa bits replaced by the
// key index (rel err 2^-12 -> p err ~1e-3, threshold 7.1e-2).
template <int CSEG>
__global__ __launch_bounds__(256, 5)
void entmax_scores_kernel(const float* __restrict__ q,
                          const unsigned short* __restrict__ khi,
                          const unsigned short* __restrict__ klo,
                          int* __restrict__ gscnt,
                          unsigned int* __restrict__ gent) {
  const int t    = threadIdx.x;
  const int wave = t >> 6;
  const int lane = t & 63;
  const int g    = lane >> 4;
  const int col  = lane & 15;

  // head-XCD affinity: bh = blk & 15 -> blk % 8 == bh % 8 under round-robin.
  const int blk  = blockIdx.x;
  const int bh   = blk & 15;
  const int kseg = (blk >> 4) & 3;
  const int qt   = blk >> 6;                   // 0..127
  const float* qp = q + ((size_t)bh * S_ + (size_t)qt * QT_A) * D_;

  // Q fragment: A row = col, d = ks*32 + g*8 + i; fold scale/2 => *1/16.
  bf16x8 qh[2], ql[2];
#pragma unroll
  for (int ks = 0; ks < 2; ++ks) {
    const float* src = qp + col * D_ + ks * 32 + g * 8;
    float4 f0 = *(const float4*)src;
    float4 f1 = *(const float4*)(src + 4);
    f0.x *= 0.0625f; f0.y *= 0.0625f; f0.z *= 0.0625f; f0.w *= 0.0625f;
    f1.x *= 0.0625f; f1.y *= 0.0625f; f1.z *= 0.0625f; f1.w *= 0.0625f;
    split8(f0, f1, qh[ks], ql[ks]);
  }

  // QK^T over this wave's 128 keys: acc[kt][j] = x[row=g*4+j][kbase+kt*16+col]
  const int kbase = kseg * 512 + wave * 128;
  f32x4 acc[KTW_A];
#pragma unroll
  for (int kt = 0; kt < KTW_A; ++kt) acc[kt] = (f32x4){0.f, 0.f, 0.f, 0.f};
#pragma unroll
  for (int kt = 0; kt < KTW_A; ++kt) {
    const size_t rowoff = ((size_t)bh * S_ + kbase + kt * 16 + col) * D_;
#pragma unroll
    for (int ks = 0; ks < 2; ++ks) {
      bf16x8 kh = *(const bf16x8*)(khi + rowoff + ks * 32 + g * 8);
      bf16x8 kl = *(const bf16x8*)(klo + rowoff + ks * 32 + g * 8);
      acc[kt] = __builtin_amdgcn_mfma_f32_16x16x32_bf16(qh[ks], kh, acc[kt], 0, 0, 0);
      acc[kt] = __builtin_amdgcn_mfma_f32_16x16x32_bf16(qh[ks], kl, acc[kt], 0, 0, 0);
      acc[kt] = __builtin_amdgcn_mfma_f32_16x16x32_bf16(ql[ks], kh, acc[kt], 0, 0, 0);
    }
  }

  // Wave-local row max over its 128 keys (16-lane col-group butterfly).
  float m4[4];
#pragma unroll
  for (int j = 0; j < 4; ++j) {
    float mm = acc[0][j];
#pragma unroll
    for (int kt = 1; kt < KTW_A; ++kt) mm = fmaxf(mm, acc[kt][j]);
    m4[j] = mm;
  }
#pragma unroll
  for (int off = 1; off < 16; off <<= 1)
#pragma unroll
    for (int j = 0; j < 4; ++j) m4[j] = fmaxf(m4[j], __shfl_xor(m4[j], off, 64));

  // Wave-subset Newton from tau0 = m_w - 1 (f_w(tau0) >= 0; s1 > 0 below
  // the subset root). Early exit when all rows in the wave converge.
  float tau[4];
#pragma unroll
  for (int j = 0; j < 4; ++j) tau[j] = m4[j] - 1.0f;
  for (int it = 0; it < ITW_A; ++it) {
    float s1[4] = {0, 0, 0, 0}, s2[4] = {0, 0, 0, 0};
#pragma unroll
    for (int kt = 0; kt < KTW_A; ++kt)
#pragma unroll
      for (int j = 0; j < 4; ++j) {
        float u = fmaxf(acc[kt][j] - tau[j], 0.f);
        s1[j] += u; s2[j] = fmaf(u, u, s2[j]);
      }
#pragma unroll
    for (int off = 1; off < 16; off <<= 1)
#pragma unroll
      for (int j = 0; j < 4; ++j) {
        s1[j] += __shfl_xor(s1[j], off, 64);
        s2[j] += __shfl_xor(s2[j], off, 64);
      }
    float ms = 0.f;
#pragma unroll
    for (int j = 0; j < 4; ++j) {
      float st = (s2[j] - 1.0f) / (2.0f * s1[j]);
      tau[j] += st;
      ms = fmaxf(ms, st);
    }
    if (__ballot(ms >= 1e-7f) == 0ull) break;    // wave-uniform exit
  }

  // Atomic-free compaction: per (kt,j) one ballot; the 16-bit field of this
  // lane's group gives slot = base + popcount(bits below col). Stores land
  // in the (row,seg) slab; counts (true, un-clamped) written once per group.
  const int seg = kseg * 4 + wave;
  int base[4] = {0, 0, 0, 0};
#pragma unroll
  for (int kt = 0; kt < KTW_A; ++kt) {
#pragma unroll
    for (int j = 0; j < 4; ++j) {
      const bool pred = acc[kt][j] > tau[j];
      const unsigned long long mb = __ballot(pred);
      const unsigned int field = (unsigned int)(mb >> (g * 16)) & 0xFFFFu;
      if (pred) {
        const int slot = base[j] + __popc(field & ((1u << col) - 1u));
        if (slot < CSEG) {
          const int rowg = bh * S_ + qt * QT_A + g * 4 + j;
          const unsigned int key = (unsigned int)(kbase + kt * 16 + col);
          const unsigned int e = (__float_as_uint(acc[kt][j]) & 0xFFFFF800u) | key;
          gent[(size_t)rowg * (NSEG * CSEG) + seg * CSEG + slot] = e;
        }
      }
      base[j] += __popc(field);
    }
  }
  if (col == 0) {
#pragma unroll
    for (int j = 0; j < 4; ++j)
      gscnt[(size_t)(bh * S_ + qt * QT_A + g * 4 + j) * NSEG + seg] = base[j];
  }
}

// ============ Phase B: exact per-row Newton + sparse PV ============
// One wave per row. Padded coalesced load of the 16 slabs, masked by the
// per-segment counts. Overflow (any segment count > CSEG; rare by
// construction, exact for ANY data): full fp32 row recompute. No barriers
// (all LDS state wave-private; same-wave LDS ops are in-order).
template <int CSEG>
__global__ __launch_bounds__(256)
void entmax_solvepv_kernel(const float* __restrict__ q,
                           const float* __restrict__ k,
                           const float* __restrict__ v,
                           const int* __restrict__ gscnt,
                           const unsigned int* __restrict__ gent,
                           float* __restrict__ out) {
  constexpr int NR = (NSEG * CSEG) / 64;       // padded regs per lane
  __shared__ int   sidx[4][SUPC];
  __shared__ float sp[4][SUPC];
  __shared__ unsigned int scnt[4];
  __shared__ float qs[4][D_];

  const int t    = threadIdx.x;
  const int wid  = t >> 6;
  const int lane = t & 63;
  const int blk  = blockIdx.x;
  const int bh   = blk & 15;                   // head-XCD affinity for V
  const int u    = blk >> 4;                   // 0..511
  const int rowg = bh * S_ + u * 4 + wid;
  const float* vp = v + (size_t)bh * S_ * D_;

  if (lane == 0) scnt[wid] = 0;

  const int cw = (lane < NSEG) ? gscnt[(size_t)rowg * NSEG + lane] : 0;
  const bool ovf = __ballot(cw > CSEG) != 0ull;

  if (!ovf) {
    float xv[NR]; int iv[NR];
#pragma unroll
    for (int r = 0; r < NR; ++r) {
      const int slot = lane + (r << 6);
      const int sg = slot / CSEG;              // CSEG is a power of 2
      const int ii = slot - sg * CSEG;
      const int cs = __shfl(cw, sg);
      const unsigned int e = gent[(size_t)rowg * (NSEG * CSEG) + slot];
      const bool valid = ii < cs;
      xv[r] = valid ? __uint_as_float(e & 0xFFFFF800u) : -1e30f;
      iv[r] = (int)(e & 0x7FFu);
    }
    float mx = xv[0];
#pragma unroll
    for (int r = 1; r < NR; ++r) mx = fmaxf(mx, xv[r]);
#pragma unroll
    for (int off = 1; off < 64; off <<= 1) mx = fmaxf(mx, __shfl_xor(mx, off, 64));
    float tau = mx - 1.0f;   // row max is always admitted (x_max > tau_w)
    for (int it = 0; it < BMAXIT; ++it) {
      float s1 = 0.f, s2 = 0.f;
#pragma unroll
      for (int r = 0; r < NR; ++r) {
        float uu = fmaxf(xv[r] - tau, 0.f);
        s1 += uu; s2 = fmaf(uu, uu, s2);
      }
#pragma unroll
      for (int off = 1; off < 64; off <<= 1) {
        s1 += __shfl_xor(s1, off, 64);
        s2 += __shfl_xor(s2, off, 64);
      }
      float step = (s2 - 1.0f) / (2.0f * s1);
      tau += step;
      if (step < 1e-7f) break;                  // lane-uniform
    }
#pragma unroll
    for (int r = 0; r < NR; ++r) {
      float uu = xv[r] - tau;
      if (uu > 0.f) {
        unsigned int slot = atomicAdd(&scnt[wid], 1u);   // LDS atomic: cheap
        if (slot < SUPC) { sidx[wid][slot] = iv[r]; sp[wid][slot] = uu * uu; }
      }
    }
  } else {
    // ---- overflow repair: exact fp32 recompute of this row (32 keys/lane).
    qs[wid][lane] = q[(size_t)rowg * D_ + lane] * 0.0625f;
    const float* kb = k + (size_t)bh * S_ * D_;
    float xs[32];
    for (int r = 0; r < 32; ++r) {
      const float* krow = kb + (size_t)(lane + (r << 6)) * D_;
      float d = 0.f;
#pragma unroll 4
      for (int dc = 0; dc < D_; dc += 4) {
        float4 kv4 = *(const float4*)(krow + dc);
        d = fmaf(qs[wid][dc + 0], kv4.x, d);
        d = fmaf(qs[wid][dc + 1], kv4.y, d);
        d = fmaf(qs[wid][dc + 2], kv4.z, d);
        d = fmaf(qs[wid][dc + 3], kv4.w, d);
      }
      xs[r] = d;
    }
    float mx = xs[0];
#pragma unroll
    for (int r = 1; r < 32; ++r) mx = fmaxf(mx, xs[r]);
#pragma unroll
    for (int off = 1; off < 64; off <<= 1) mx = fmaxf(mx, __shfl_xor(mx, off, 64));
    float tau = mx - 1.0f;
    for (int it = 0; it < BMAXIT; ++it) {
      float s1 = 0.f, s2 = 0.f;
#pragma unroll
      for (int r = 0; r < 32; ++r) {
        float uu = fmaxf(xs[r] - tau, 0.f);
        s1 += uu; s2 = fmaf(uu, uu, s2);
      }
#pragma unroll
      for (int off = 1; off < 64; off <<= 1) {
        s1 += __shfl_xor(s1, off, 64);
        s2 += __shfl_xor(s2, off, 64);
      }
      float step = (s2 - 1.0f) / (2.0f * s1);
      tau += step;
      if (step < 1e-7f) break;
    }
#pragma unroll
    for (int r = 0; r < 32; ++r) {
      float uu = xs[r] - tau;
      if (uu > 0.f) {
        unsigned int slot = atomicAdd(&scnt[wid], 1u);
        if (slot < SUPC) { sidx[wid][slot] = lane + (r << 6); sp[wid][slot] = uu * uu; }
      }
    }
  }

  int sn = (int)scnt[wid]; if (sn > SUPC) sn = SUPC;
  float s = 0.f;
#pragma unroll 4
  for (int i = 0; i < sn; ++i)
    s = fmaf(sp[wid][i], vp[(size_t)sidx[wid][i] * D_ + lane], s);
  out[(size_t)rowg * D_ + lane] = s;
}

// ============ Fallback: R5 single-kernel path (verbatim) ============
template <bool PRE>
__global__ __launch_bounds__(BLOCK_F, 4)
void entmax_attn_kernel(const float* __restrict__ q,
                        const float* __restrict__ k,
                        const unsigned short* __restrict__ khi,
                        const unsigned short* __restrict__ klo,
                        const float* __restrict__ v,
                        float* __restrict__ out) {
  __shared__ float redM[NW_F][QT_F];
  __shared__ float redS1[2][NW_F][QT_F];
  __shared__ float redS2[2][NW_F][QT_F];
  __shared__ unsigned int cnt[QT_F];
  __shared__ int   lidx[QT_F][CAP_F];
  __shared__ float lval[QT_F][CAP_F];

  const int t    = threadIdx.x;
  const int wid  = t >> 6;
  const int lane = t & 63;
  const int g    = lane >> 4;
  const int col  = lane & 15;
  const int rowL = lane & 31;

  const int blk = blockIdx.x;
  const int bh  = blk & 15;
  const int qt  = blk >> 4;
  const float* qp = q + ((size_t)bh * S_ + (size_t)qt * QT_F) * D_;
  const float* kp = k + (size_t)bh * S_ * D_;
  const float* vp = v + (size_t)bh * S_ * D_;
  float* op = out + ((size_t)bh * S_ + (size_t)qt * QT_F) * D_;

  if (t < QT_F) cnt[t] = 0;

  bf16x8 qh[2][2], ql[2][2];
#pragma unroll
  for (int f = 0; f < 2; ++f)
#pragma unroll
    for (int ks = 0; ks < 2; ++ks) {
      const float* src = qp + (f * 16 + col) * D_ + ks * 32 + g * 8;
      float4 f0 = *(const float4*)src;
      float4 f1 = *(const float4*)(src + 4);
      f0.x *= 0.0625f; f0.y *= 0.0625f; f0.z *= 0.0625f; f0.w *= 0.0625f;
      f1.x *= 0.0625f; f1.y *= 0.0625f; f1.z *= 0.0625f; f1.w *= 0.0625f;
      split8(f0, f1, qh[f][ks], ql[f][ks]);
    }

  f32x4 acc[2][KTW_F];
#pragma unroll
  for (int f = 0; f < 2; ++f)
#pragma unroll
    for (int kt = 0; kt < KTW_F; ++kt) acc[f][kt] = (f32x4){0.f, 0.f, 0.f, 0.f};
#pragma unroll
  for (int kt = 0; kt < KTW_F; ++kt) {
    const size_t rowoff = (size_t)(wid * 128 + kt * 16 + col) * D_;
#pragma unroll
    for (int ks = 0; ks < 2; ++ks) {
      bf16x8 kh, kl;
      if (PRE) {
        const size_t eoff = (size_t)bh * S_ * D_ + rowoff + ks * 32 + g * 8;
        kh = *(const bf16x8*)(khi + eoff);
        kl = *(const bf16x8*)(klo + eoff);
      } else {
        const float* src = kp + rowoff + ks * 32 + g * 8;
        split8(*(const float4*)src, *(const float4*)(src + 4), kh, kl);
      }
#pragma unroll
      for (int f = 0; f < 2; ++f) {
        acc[f][kt] = __builtin_amdgcn_mfma_f32_16x16x32_bf16(qh[f][ks], kh, acc[f][kt], 0, 0, 0);
        acc[f][kt] = __builtin_amdgcn_mfma_f32_16x16x32_bf16(qh[f][ks], kl, acc[f][kt], 0, 0, 0);
        acc[f][kt] = __builtin_amdgcn_mfma_f32_16x16x32_bf16(ql[f][ks], kh, acc[f][kt], 0, 0, 0);
      }
    }
  }

  {
    float m4[2][4];
#pragma unroll
    for (int f = 0; f < 2; ++f)
#pragma unroll
      for (int j = 0; j < 4; ++j) {
        float mm = acc[f][0][j];
#pragma unroll
        for (int kt = 1; kt < KTW_F; ++kt) mm = fmaxf(mm, acc[f][kt][j]);
        m4[f][j] = mm;
      }
#pragma unroll
    for (int off = 1; off < 16; off <<= 1)
#pragma unroll
      for (int f = 0; f < 2; ++f)
#pragma unroll
        for (int j = 0; j < 4; ++j)
          m4[f][j] = fmaxf(m4[f][j], __shfl_xor(m4[f][j], off, 64));
    if (col == 0) {
#pragma unroll
      for (int f = 0; f < 2; ++f)
#pragma unroll
        for (int j = 0; j < 4; ++j) redM[wid][f * 16 + g * 4 + j] = m4[f][j];
    }
  }
  __syncthreads();

  float tauRow;
  {
    float mm = redM[0][rowL];
#pragma unroll
    for (int w = 1; w < NW_F; ++w) mm = fmaxf(mm, redM[w][rowL]);
    tauRow = mm - 1.0f;
  }
  float tau[2][4];
#pragma unroll
  for (int f = 0; f < 2; ++f)
#pragma unroll
    for (int j = 0; j < 4; ++j) tau[f][j] = __shfl(tauRow, f * 16 + g * 4 + j);

  for (int it = 0; it < ITPRE_F; ++it) {
    const int b = it & 1;
    float s1[2][4] = {{0,0,0,0},{0,0,0,0}}, s2[2][4] = {{0,0,0,0},{0,0,0,0}};
#pragma unroll
    for (int kt = 0; kt < KTW_F; ++kt)
#pragma unroll
      for (int f = 0; f < 2; ++f)
#pragma unroll
        for (int j = 0; j < 4; ++j) {
          float u = fmaxf(acc[f][kt][j] - tau[f][j], 0.f);
          s1[f][j] += u; s2[f][j] = fmaf(u, u, s2[f][j]);
        }
#pragma unroll
    for (int off = 1; off < 16; off <<= 1)
#pragma unroll
      for (int f = 0; f < 2; ++f)
#pragma unroll
        for (int j = 0; j < 4; ++j) {
          s1[f][j] += __shfl_xor(s1[f][j], off, 64);
          s2[f][j] += __shfl_xor(s2[f][j], off, 64);
        }
    if (col == 0) {
#pragma unroll
      for (int f = 0; f < 2; ++f)
#pragma unroll
        for (int j = 0; j < 4; ++j) {
          redS1[b][wid][f * 16 + g * 4 + j] = s1[f][j];
          redS2[b][wid][f * 16 + g * 4 + j] = s2[f][j];
        }
    }
    __syncthreads();
    const float* pS = (lane < 32) ? &redS1[b][0][rowL] : &redS2[b][0][rowL];
    float T = 0.f;
#pragma unroll
    for (int w = 0; w < NW_F; ++w) T += pS[w * QT_F];
    float other = __shfl_xor(T, 32, 64);
    float step_r = (other - 1.0f) / (2.0f * T);
    if (lane < 32) tauRow += step_r;
#pragma unroll
    for (int f = 0; f < 2; ++f)
#pragma unroll
      for (int j = 0; j < 4; ++j)
        tau[f][j] += __shfl(step_r, f * 16 + g * 4 + j);
  }

#pragma unroll
  for (int kt = 0; kt < KTW_F; ++kt)
#pragma unroll
    for (int f = 0; f < 2; ++f)
#pragma unroll
      for (int j = 0; j < 4; ++j) {
        float x = acc[f][kt][j];
        if (x > tau[f][j]) {
          const int row = f * 16 + g * 4 + j;
          unsigned int s = atomicAdd(&cnt[row], 1u);
          if (s < CAP_F) {
            lidx[row][s] = wid * 128 + kt * 16 + col;
            lval[row][s] = x;
          }
        }
      }
  __syncthreads();

  for (int rr = 0; rr < 2; ++rr) {
    const int row = wid * 2 + rr;
    int n = (int)cnt[row]; if (n > CAP_F) n = CAP_F;
    float xv[4];
#pragma unroll
    for (int r = 0; r < 4; ++r) {
      const int i = lane + 64 * r;
      xv[r] = (i < n) ? lval[row][i] : -1e30f;
    }
    float tw = __shfl(tauRow, row);
    for (int it = 0; it < WMAXIT_F; ++it) {
      float s1 = 0.f, s2 = 0.f;
#pragma unroll
      for (int r = 0; r < 4; ++r) {
        float u = fmaxf(xv[r] - tw, 0.f);
        s1 += u; s2 = fmaf(u, u, s2);
      }
#pragma unroll
      for (int off = 1; off < 64; off <<= 1) {
        s1 += __shfl_xor(s1, off, 64);
        s2 += __shfl_xor(s2, off, 64);
      }
      float step = (s2 - 1.0f) / (2.0f * s1);
      tw += step;
      if (step < 1e-7f) break;
    }
#pragma unroll
    for (int r = 0; r < 4; ++r) {
      const int i = lane + 64 * r;
      if (i < n) {
        float u = fmaxf(xv[r] - tw, 0.f);
        lval[row][i] = u * u;
      }
    }
    float s = 0.f;
#pragma unroll 4
    for (int i = 0; i < n; ++i) {
      s = fmaf(lval[row][i], vp[(size_t)lidx[row][i] * D_ + lane], s);
    }
    op[row * D_ + lane] = s;
  }
}

extern "C" void kernel_launch(void* const* d_in, const int* in_sizes, int n_in,
                              void* d_out, int out_size, void* d_ws, size_t ws_size,
                              hipStream_t stream) {
  const float* q = (const float*)d_in[0];
  const float* k = (const float*)d_in[1];
  const float* v = (const float*)d_in[2];
  float* out = (float*)d_out;

  const size_t khi_b = (size_t)KELEMS * 2;                 // 4 MB each
  const size_t cnt_b = (size_t)NROWS * NSEG * 4;           // 2 MB
  const size_t base  = 2 * khi_b + cnt_b;                  // ~10.5 MB
  const size_t ent32 = (size_t)NROWS * NSEG * 32 * 4;      // 67 MB
  const size_t ent16 = (size_t)NROWS * NSEG * 16 * 4;      // 33.5 MB

  int cseg = 0;
  if (d_ws != nullptr) {
    if      (ws_size >= base + ent32) cseg = 32;           // ~78 MB
    else if (ws_size >= base + ent16) cseg = 16;           // ~44 MB
  }

  if (cseg != 0) {
    unsigned short* khi = (unsigned short*)d_ws;
    unsigned short* klo = khi + KELEMS;
    int* gscnt = (int*)((char*)d_ws + 2 * khi_b);
    unsigned int* gent = (unsigned int*)((char*)d_ws + base);
    ksplit_kernel<<<dim3(KELEMS / (256 * 4)), dim3(256), 0, stream>>>(k, khi, klo);
    const dim3 gA(BH_ * 4 * (S_ / QT_A));
    const dim3 gB(NROWS / 4);
    if (cseg == 32) {
      entmax_scores_kernel<32><<<gA, dim3(256), 0, stream>>>(q, khi, klo, gscnt, gent);
      entmax_solvepv_kernel<32><<<gB, dim3(256), 0, stream>>>(q, k, v, gscnt, gent, out);
    } else {
      entmax_scores_kernel<16><<<gA, dim3(256), 0, stream>>>(q, khi, klo, gscnt, gent);
      entmax_solvepv_kernel<16><<<gB, dim3(256), 0, stream>>>(q, k, v, gscnt, gent, out);
    }
  } else if (d_ws != nullptr && ws_size >= 2 * khi_b) {
    unsigned short* khi = (unsigned short*)d_ws;
    unsigned short* klo = khi + KELEMS;
    ksplit_kernel<<<dim3(KELEMS / (256 * 4)), dim3(256), 0, stream>>>(k, khi, klo);
    entmax_attn_kernel<true><<<dim3(BH_ * (S_ / QT_F)), dim3(BLOCK_F), 0, stream>>>(
        q, k, khi, klo, v, out);
  } else {
    entmax_attn_kernel<false><<<dim3(BH_ * (S_ / QT_F)), dim3(BLOCK_F), 0, stream>>>(
        q, k, nullptr, nullptr, v, out);
  }
}

// Round 9
// 300.968 us; speedup vs baseline: 2.9477x; 1.0224x over previous
//
#include <hip/hip_runtime.h>
#include <math.h>

// Problem constants (B=2, H=8, S=2048, D=64)
#define BH_    16
#define S_     2048
#define D_     64
#define KELEMS (BH_ * S_ * D_)       // 2,097,152 K elements
#define NROWS  (BH_ * S_)            // 32,768 query rows
#define NSEG   16                    // wave-segments per row (4 kseg x 4 waves)

// ---- two-phase path geometry
#define SUPC   256      // support cap/row in phase B (typ. support ~20-40)
#define QT_A   16       // queries per phase-A block (MFMA M)
#define KTW_A  8        // 16-key tiles per wave (128 keys/wave, 4 waves)
#define ITW_A  5        // FIXED wave-subset Newton iterations (R8: early-exit
                        // ran ~7 passes; 5 fixed trades ~2 passes for ~1.5-2x
                        // more candidates, well under CSEG=32)
#define BMAXIT 32       // phase-B Newton max iterations (early-exit, ~4-6 typ)

// ---- fallback (R5 single-kernel) geometry
#define QT_F    32
#define BLOCK_F 1024
#define NW_F    16
#define KTW_F   8
#define CAP_F   256
#define ITPRE_F 5
#define WMAXIT_F 16

typedef __attribute__((ext_vector_type(8))) short bf16x8;   // 8 bf16 = 4 VGPR
typedef __attribute__((ext_vector_type(4))) float f32x4;

// Exact hi/lo bf16 truncation split of 8 consecutive floats.
// x = hi + lo + eps, |eps| <= 2^-15 |x|; products use hh + hl + lh (drop ll).
__device__ __forceinline__ void split8(const float4 f0, const float4 f1,
                                       bf16x8& hi, bf16x8& lo) {
  union { bf16x8 v; unsigned int u[4]; } H, L;
  const float ff[8] = {f0.x, f0.y, f0.z, f0.w, f1.x, f1.y, f1.z, f1.w};
#pragma unroll
  for (int p = 0; p < 4; ++p) {
    unsigned int b0 = __float_as_uint(ff[2 * p]);
    unsigned int b1 = __float_as_uint(ff[2 * p + 1]);
    unsigned int h0 = b0 & 0xFFFF0000u;
    unsigned int h1 = b1 & 0xFFFF0000u;
    H.u[p] = (h0 >> 16) | h1;                       // lo short = elem 2p
    float l0 = ff[2 * p]     - __uint_as_float(h0); // exact in fp32
    float l1 = ff[2 * p + 1] - __uint_as_float(h1);
    L.u[p] = (__float_as_uint(l0) >> 16) | (__float_as_uint(l1) & 0xFFFF0000u);
  }
  hi = H.v; lo = L.v;
}

// Prepass: K fp32 -> (Khi, Klo) bf16 (same element order).
__global__ __launch_bounds__(256)
void ksplit_kernel(const float* __restrict__ k,
                   unsigned short* __restrict__ khi,
                   unsigned short* __restrict__ klo) {
  const int i = (blockIdx.x * 256 + threadIdx.x) * 4;
  float4 x = *(const float4*)(k + i);
  ushort4 h, l;
  {
    unsigned int b;
    b = __float_as_uint(x.x); h.x = (unsigned short)(b >> 16);
    l.x = (unsigned short)(__float_as_uint(x.x - __uint_as_float(b & 0xFFFF0000u)) >> 16);
    b = __float_as_uint(x.y); h.y = (unsigned short)(b >> 16);
    l.y = (unsigned short)(__float_as_uint(x.y - __uint_as_float(b & 0xFFFF0000u)) >> 16);
    b = __float_as_uint(x.z); h.z = (unsigned short)(b >> 16);
    l.z = (unsigned short)(__float_as_uint(x.z - __uint_as_float(b & 0xFFFF0000u)) >> 16);
    b = __float_as_uint(x.w); h.w = (unsigned short)(b >> 16);
    l.w = (unsigned short)(__float_as_uint(x.w - __uint_as_float(b & 0xFFFF0000u)) >> 16);
  }
  *(ushort4*)(khi + i) = h;
  *(ushort4*)(klo + i) = l;
}

// ============ Phase A: MFMA scores + ATOMIC-FREE wave compaction ============
// Block = 16 q x 512 keys; wave owns 128 keys (segment seg = kseg*4+wave).
// Wave-subset Newton from below: every iterate tau_w <= subset root <= tau*,
// so admitting {x > tau_w} keeps the full support for ANY data. Slot
// assignment is ballot+popcount (R7: global atomicAdd chain was ~680us).
// Entry = fp32 score with low 11 mantissa bits replaced by key index.
// NEW (R9): fixed 5 iterations (no ballot-exit), and the per-segment tau is
// PUBLISHED so phase B can start from max(tau_seg) instead of max-1.
template <int CSEG>
__global__ __launch_bounds__(256, 5)
void entmax_scores_kernel(const float* __restrict__ q,
                          const unsigned short* __restrict__ khi,
                          const unsigned short* __restrict__ klo,
                          int* __restrict__ gscnt,
                          float* __restrict__ gstau,
                          unsigned int* __restrict__ gent) {
  const int t    = threadIdx.x;
  const int wave = t >> 6;
  const int lane = t & 63;
  const int g    = lane >> 4;
  const int col  = lane & 15;

  // head-XCD affinity: bh = blk & 15 -> blk % 8 == bh % 8 under round-robin.
  const int blk  = blockIdx.x;
  const int bh   = blk & 15;
  const int kseg = (blk >> 4) & 3;
  const int qt   = blk >> 6;                   // 0..127
  const float* qp = q + ((size_t)bh * S_ + (size_t)qt * QT_A) * D_;

  // Q fragment: A row = col, d = ks*32 + g*8 + i; fold scale/2 => *1/16.
  bf16x8 qh[2], ql[2];
#pragma unroll
  for (int ks = 0; ks < 2; ++ks) {
    const float* src = qp + col * D_ + ks * 32 + g * 8;
    float4 f0 = *(const float4*)src;
    float4 f1 = *(const float4*)(src + 4);
    f0.x *= 0.0625f; f0.y *= 0.0625f; f0.z *= 0.0625f; f0.w *= 0.0625f;
    f1.x *= 0.0625f; f1.y *= 0.0625f; f1.z *= 0.0625f; f1.w *= 0.0625f;
    split8(f0, f1, qh[ks], ql[ks]);
  }

  // QK^T over this wave's 128 keys: acc[kt][j] = x[row=g*4+j][kbase+kt*16+col]
  const int kbase = kseg * 512 + wave * 128;
  f32x4 acc[KTW_A];
#pragma unroll
  for (int kt = 0; kt < KTW_A; ++kt) acc[kt] = (f32x4){0.f, 0.f, 0.f, 0.f};
#pragma unroll
  for (int kt = 0; kt < KTW_A; ++kt) {
    const size_t rowoff = ((size_t)bh * S_ + kbase + kt * 16 + col) * D_;
#pragma unroll
    for (int ks = 0; ks < 2; ++ks) {
      bf16x8 kh = *(const bf16x8*)(khi + rowoff + ks * 32 + g * 8);
      bf16x8 kl = *(const bf16x8*)(klo + rowoff + ks * 32 + g * 8);
      acc[kt] = __builtin_amdgcn_mfma_f32_16x16x32_bf16(qh[ks], kh, acc[kt], 0, 0, 0);
      acc[kt] = __builtin_amdgcn_mfma_f32_16x16x32_bf16(qh[ks], kl, acc[kt], 0, 0, 0);
      acc[kt] = __builtin_amdgcn_mfma_f32_16x16x32_bf16(ql[ks], kh, acc[kt], 0, 0, 0);
    }
  }

  // Wave-local row max over its 128 keys (16-lane col-group butterfly).
  float m4[4];
#pragma unroll
  for (int j = 0; j < 4; ++j) {
    float mm = acc[0][j];
#pragma unroll
    for (int kt = 1; kt < KTW_A; ++kt) mm = fmaxf(mm, acc[kt][j]);
    m4[j] = mm;
  }
#pragma unroll
  for (int off = 1; off < 16; off <<= 1)
#pragma unroll
    for (int j = 0; j < 4; ++j) m4[j] = fmaxf(m4[j], __shfl_xor(m4[j], off, 64));

  // Wave-subset Newton from tau0 = m_w - 1; s2 >= 1 -> s1 >= 1 below the
  // subset root, so the division is safe. Fixed ITW_A iterations.
  float tau[4];
#pragma unroll
  for (int j = 0; j < 4; ++j) tau[j] = m4[j] - 1.0f;
  for (int it = 0; it < ITW_A; ++it) {
    float s1[4] = {0, 0, 0, 0}, s2[4] = {0, 0, 0, 0};
#pragma unroll
    for (int kt = 0; kt < KTW_A; ++kt)
#pragma unroll
      for (int j = 0; j < 4; ++j) {
        float u = fmaxf(acc[kt][j] - tau[j], 0.f);
        s1[j] += u; s2[j] = fmaf(u, u, s2[j]);
      }
#pragma unroll
    for (int off = 1; off < 16; off <<= 1)
#pragma unroll
      for (int j = 0; j < 4; ++j) {
        s1[j] += __shfl_xor(s1[j], off, 64);
        s2[j] += __shfl_xor(s2[j], off, 64);
      }
#pragma unroll
    for (int j = 0; j < 4; ++j) tau[j] += (s2[j] - 1.0f) / (2.0f * s1[j]);
  }

  // Atomic-free compaction: one ballot per (kt,j); slot = prefix popcount
  // within the row's 16-lane group. True (un-clamped) counts + taus written
  // once per group: overflow detection AND the phase-B warm start.
  const int seg = kseg * 4 + wave;
  int base[4] = {0, 0, 0, 0};
#pragma unroll
  for (int kt = 0; kt < KTW_A; ++kt) {
#pragma unroll
    for (int j = 0; j < 4; ++j) {
      const bool pred = acc[kt][j] > tau[j];
      const unsigned long long mb = __ballot(pred);
      const unsigned int field = (unsigned int)(mb >> (g * 16)) & 0xFFFFu;
      if (pred) {
        const int slot = base[j] + __popc(field & ((1u << col) - 1u));
        if (slot < CSEG) {
          const int rowg = bh * S_ + qt * QT_A + g * 4 + j;
          const unsigned int key = (unsigned int)(kbase + kt * 16 + col);
          const unsigned int e = (__float_as_uint(acc[kt][j]) & 0xFFFFF800u) | key;
          gent[(size_t)rowg * (NSEG * CSEG) + seg * CSEG + slot] = e;
        }
      }
      base[j] += __popc(field);
    }
  }
  if (col == 0) {
#pragma unroll
    for (int j = 0; j < 4; ++j) {
      const size_t o = (size_t)(bh * S_ + qt * QT_A + g * 4 + j) * NSEG + seg;
      gscnt[o] = base[j];
      gstau[o] = tau[j];
    }
  }
}

// ============ Phase B: exact per-row Newton + sparse PV ============
// One wave per row. Warm start: tau0 = max over the 16 published segment
// roots (each <= tau*; the segment holding the global max gives tau0 >=
// m-1). Newton converges in ~4-6 iters. Overflow (any segment count >
// CSEG): exact full-row fp32 recompute. PV is 4 entry-subgroups x 16
// d-lanes (float4) -> 4 independent gather chains + 2-level reduce.
template <int CSEG>
__global__ __launch_bounds__(256)
void entmax_solvepv_kernel(const float* __restrict__ q,
                           const float* __restrict__ k,
                           const float* __restrict__ v,
                           const int* __restrict__ gscnt,
                           const float* __restrict__ gstau,
                           const unsigned int* __restrict__ gent,
                           float* __restrict__ out) {
  constexpr int NR = (NSEG * CSEG) / 64;       // padded regs per lane
  __shared__ int   sidx[4][SUPC];
  __shared__ float sp[4][SUPC];
  __shared__ unsigned int scnt[4];
  __shared__ float qs[4][D_];

  const int t    = threadIdx.x;
  const int wid  = t >> 6;
  const int lane = t & 63;
  const int blk  = blockIdx.x;
  const int bh   = blk & 15;                   // head-XCD affinity for V
  const int u    = blk >> 4;                   // 0..511
  const int rowg = bh * S_ + u * 4 + wid;
  const float* vp = v + (size_t)bh * S_ * D_;

  if (lane == 0) scnt[wid] = 0;

  const int cw = (lane < NSEG) ? gscnt[(size_t)rowg * NSEG + lane] : 0;
  const bool ovf = __ballot(cw > CSEG) != 0ull;

  if (!ovf) {
    // warm start: max of the 16 segment taus (lanes >= 16 padded to -inf).
    float ts = (lane < NSEG) ? gstau[(size_t)rowg * NSEG + lane] : -3e38f;
#pragma unroll
    for (int off = 1; off < 64; off <<= 1) ts = fmaxf(ts, __shfl_xor(ts, off, 64));
    float tau = ts;

    float xv[NR]; int iv[NR];
#pragma unroll
    for (int r = 0; r < NR; ++r) {
      const int slot = lane + (r << 6);
      const int sg = slot / CSEG;              // CSEG is a power of 2
      const int ii = slot - sg * CSEG;
      const int cs = __shfl(cw, sg);
      const unsigned int e = gent[(size_t)rowg * (NSEG * CSEG) + slot];
      const bool valid = ii < cs;
      xv[r] = valid ? __uint_as_float(e & 0xFFFFF800u) : -1e30f;
      iv[r] = (int)(e & 0x7FFu);
    }
    for (int it = 0; it < BMAXIT; ++it) {
      float s1 = 0.f, s2 = 0.f;
#pragma unroll
      for (int r = 0; r < NR; ++r) {
        float uu = fmaxf(xv[r] - tau, 0.f);
        s1 += uu; s2 = fmaf(uu, uu, s2);
      }
#pragma unroll
      for (int off = 1; off < 64; off <<= 1) {
        s1 += __shfl_xor(s1, off, 64);
        s2 += __shfl_xor(s2, off, 64);
      }
      float step = (s2 - 1.0f) / (2.0f * s1);  // s1 >= 1 below the root
      tau += step;
      if (step < 1e-7f) break;                 // lane-uniform
    }
#pragma unroll
    for (int r = 0; r < NR; ++r) {
      float uu = xv[r] - tau;
      if (uu > 0.f) {
        unsigned int slot = atomicAdd(&scnt[wid], 1u);   // LDS atomic: cheap
        if (slot < SUPC) { sidx[wid][slot] = iv[r]; sp[wid][slot] = uu * uu; }
      }
    }
  } else {
    // ---- overflow repair: exact fp32 recompute of this row (32 keys/lane).
    qs[wid][lane] = q[(size_t)rowg * D_ + lane] * 0.0625f;
    const float* kb = k + (size_t)bh * S_ * D_;
    float xs[32];
    for (int r = 0; r < 32; ++r) {
      const float* krow = kb + (size_t)(lane + (r << 6)) * D_;
      float d = 0.f;
#pragma unroll 4
      for (int dc = 0; dc < D_; dc += 4) {
        float4 kv4 = *(const float4*)(krow + dc);
        d = fmaf(qs[wid][dc + 0], kv4.x, d);
        d = fmaf(qs[wid][dc + 1], kv4.y, d);
        d = fmaf(qs[wid][dc + 2], kv4.z, d);
        d = fmaf(qs[wid][dc + 3], kv4.w, d);
      }
      xs[r] = d;
    }
    float mx = xs[0];
#pragma unroll
    for (int r = 1; r < 32; ++r) mx = fmaxf(mx, xs[r]);
#pragma unroll
    for (int off = 1; off < 64; off <<= 1) mx = fmaxf(mx, __shfl_xor(mx, off, 64));
    float tau = mx - 1.0f;
    for (int it = 0; it < BMAXIT; ++it) {
      float s1 = 0.f, s2 = 0.f;
#pragma unroll
      for (int r = 0; r < 32; ++r) {
        float uu = fmaxf(xs[r] - tau, 0.f);
        s1 += uu; s2 = fmaf(uu, uu, s2);
      }
#pragma unroll
      for (int off = 1; off < 64; off <<= 1) {
        s1 += __shfl_xor(s1, off, 64);
        s2 += __shfl_xor(s2, off, 64);
      }
      float step = (s2 - 1.0f) / (2.0f * s1);
      tau += step;
      if (step < 1e-7f) break;
    }
#pragma unroll
    for (int r = 0; r < 32; ++r) {
      float uu = xs[r] - tau;
      if (uu > 0.f) {
        unsigned int slot = atomicAdd(&scnt[wid], 1u);
        if (slot < SUPC) { sidx[wid][slot] = lane + (r << 6); sp[wid][slot] = uu * uu; }
      }
    }
  }

  // ---- parallel PV: entry subgroup eg = lane>>4 (stride-4 over support),
  // d-column d4 = lane&15 (float4). 4 independent LDS->V chains; 2-level
  // float4 butterfly; lanes 0-15 write the row.
  int sn = (int)scnt[wid]; if (sn > SUPC) sn = SUPC;
  const int eg = lane >> 4;
  const int d4 = lane & 15;
  float4 a4 = {0.f, 0.f, 0.f, 0.f};
  for (int i = eg; i < sn; i += 4) {
    const float pv = sp[wid][i];               // broadcast within the group
    const float4 vv = *(const float4*)&vp[(size_t)sidx[wid][i] * D_ + d4 * 4];
    a4.x = fmaf(pv, vv.x, a4.x); a4.y = fmaf(pv, vv.y, a4.y);
    a4.z = fmaf(pv, vv.z, a4.z); a4.w = fmaf(pv, vv.w, a4.w);
  }
#pragma unroll
  for (int off = 16; off < 64; off <<= 1) {
    a4.x += __shfl_xor(a4.x, off, 64);
    a4.y += __shfl_xor(a4.y, off, 64);
    a4.z += __shfl_xor(a4.z, off, 64);
    a4.w += __shfl_xor(a4.w, off, 64);
  }
  if (lane < 16)
    *(float4*)&out[(size_t)rowg * D_ + d4 * 4] = a4;
}

// ============ Fallback: R5 single-kernel path (verbatim) ============
template <bool PRE>
__global__ __launch_bounds__(BLOCK_F, 4)
void entmax_attn_kernel(const float* __restrict__ q,
                        const float* __restrict__ k,
                        const unsigned short* __restrict__ khi,
                        const unsigned short* __restrict__ klo,
                        const float* __restrict__ v,
                        float* __restrict__ out) {
  __shared__ float redM[NW_F][QT_F];
  __shared__ float redS1[2][NW_F][QT_F];
  __shared__ float redS2[2][NW_F][QT_F];
  __shared__ unsigned int cnt[QT_F];
  __shared__ int   lidx[QT_F][CAP_F];
  __shared__ float lval[QT_F][CAP_F];

  const int t    = threadIdx.x;
  const int wid  = t >> 6;
  const int lane = t & 63;
  const int g    = lane >> 4;
  const int col  = lane & 15;
  const int rowL = lane & 31;

  const int blk = blockIdx.x;
  const int bh  = blk & 15;
  const int qt  = blk >> 4;
  const float* qp = q + ((size_t)bh * S_ + (size_t)qt * QT_F) * D_;
  const float* kp = k + (size_t)bh * S_ * D_;
  const float* vp = v + (size_t)bh * S_ * D_;
  float* op = out + ((size_t)bh * S_ + (size_t)qt * QT_F) * D_;

  if (t < QT_F) cnt[t] = 0;

  bf16x8 qh[2][2], ql[2][2];
#pragma unroll
  for (int f = 0; f < 2; ++f)
#pragma unroll
    for (int ks = 0; ks < 2; ++ks) {
      const float* src = qp + (f * 16 + col) * D_ + ks * 32 + g * 8;
      float4 f0 = *(const float4*)src;
      float4 f1 = *(const float4*)(src + 4);
      f0.x *= 0.0625f; f0.y *= 0.0625f; f0.z *= 0.0625f; f0.w *= 0.0625f;
      f1.x *= 0.0625f; f1.y *= 0.0625f; f1.z *= 0.0625f; f1.w *= 0.0625f;
      split8(f0, f1, qh[f][ks], ql[f][ks]);
    }

  f32x4 acc[2][KTW_F];
#pragma unroll
  for (int f = 0; f < 2; ++f)
#pragma unroll
    for (int kt = 0; kt < KTW_F; ++kt) acc[f][kt] = (f32x4){0.f, 0.f, 0.f, 0.f};
#pragma unroll
  for (int kt = 0; kt < KTW_F; ++kt) {
    const size_t rowoff = (size_t)(wid * 128 + kt * 16 + col) * D_;
#pragma unroll
    for (int ks = 0; ks < 2; ++ks) {
      bf16x8 kh, kl;
      if (PRE) {
        const size_t eoff = (size_t)bh * S_ * D_ + rowoff + ks * 32 + g * 8;
        kh = *(const bf16x8*)(khi + eoff);
        kl = *(const bf16x8*)(klo + eoff);
      } else {
        const float* src = kp + rowoff + ks * 32 + g * 8;
        split8(*(const float4*)src, *(const float4*)(src + 4), kh, kl);
      }
#pragma unroll
      for (int f = 0; f < 2; ++f) {
        acc[f][kt] = __builtin_amdgcn_mfma_f32_16x16x32_bf16(qh[f][ks], kh, acc[f][kt], 0, 0, 0);
        acc[f][kt] = __builtin_amdgcn_mfma_f32_16x16x32_bf16(qh[f][ks], kl, acc[f][kt], 0, 0, 0);
        acc[f][kt] = __builtin_amdgcn_mfma_f32_16x16x32_bf16(ql[f][ks], kh, acc[f][kt], 0, 0, 0);
      }
    }
  }

  {
    float m4[2][4];
#pragma unroll
    for (int f = 0; f < 2; ++f)
#pragma unroll
      for (int j = 0; j < 4; ++j) {
        float mm = acc[f][0][j];
#pragma unroll
        for (int kt = 1; kt < KTW_F; ++kt) mm = fmaxf(mm, acc[f][kt][j]);
        m4[f][j] = mm;
      }
#pragma unroll
    for (int off = 1; off < 16; off <<= 1)
#pragma unroll
      for (int f = 0; f < 2; ++f)
#pragma unroll
        for (int j = 0; j < 4; ++j)
          m4[f][j] = fmaxf(m4[f][j], __shfl_xor(m4[f][j], off, 64));
    if (col == 0) {
#pragma unroll
      for (int f = 0; f < 2; ++f)
#pragma unroll
        for (int j = 0; j < 4; ++j) redM[wid][f * 16 + g * 4 + j] = m4[f][j];
    }
  }
  __syncthreads();

  float tauRow;
  {
    float mm = redM[0][rowL];
#pragma unroll
    for (int w = 1; w < NW_F; ++w) mm = fmaxf(mm, redM[w][rowL]);
    tauRow = mm - 1.0f;
  }
  float tau[2][4];
#pragma unroll
  for (int f = 0; f < 2; ++f)
#pragma unroll
    for (int j = 0; j < 4; ++j) tau[f][j] = __shfl(tauRow, f * 16 + g * 4 + j);

  for (int it = 0; it < ITPRE_F; ++it) {
    const int b = it & 1;
    float s1[2][4] = {{0,0,0,0},{0,0,0,0}}, s2[2][4] = {{0,0,0,0},{0,0,0,0}};
#pragma unroll
    for (int kt = 0; kt < KTW_F; ++kt)
#pragma unroll
      for (int f = 0; f < 2; ++f)
#pragma unroll
        for (int j = 0; j < 4; ++j) {
          float u = fmaxf(acc[f][kt][j] - tau[f][j], 0.f);
          s1[f][j] += u; s2[f][j] = fmaf(u, u, s2[f][j]);
        }
#pragma unroll
    for (int off = 1; off < 16; off <<= 1)
#pragma unroll
      for (int f = 0; f < 2; ++f)
#pragma unroll
        for (int j = 0; j < 4; ++j) {
          s1[f][j] += __shfl_xor(s1[f][j], off, 64);
          s2[f][j] += __shfl_xor(s2[f][j], off, 64);
        }
    if (col == 0) {
#pragma unroll
      for (int f = 0; f < 2; ++f)
#pragma unroll
        for (int j = 0; j < 4; ++j) {
          redS1[b][wid][f * 16 + g * 4 + j] = s1[f][j];
          redS2[b][wid][f * 16 + g * 4 + j] = s2[f][j];
        }
    }
    __syncthreads();
    const float* pS = (lane < 32) ? &redS1[b][0][rowL] : &redS2[b][0][rowL];
    float T = 0.f;
#pragma unroll
    for (int w = 0; w < NW_F; ++w) T += pS[w * QT_F];
    float other = __shfl_xor(T, 32, 64);
    float step_r = (other - 1.0f) / (2.0f * T);
    if (lane < 32) tauRow += step_r;
#pragma unroll
    for (int f = 0; f < 2; ++f)
#pragma unroll
      for (int j = 0; j < 4; ++j)
        tau[f][j] += __shfl(step_r, f * 16 + g * 4 + j);
  }

#pragma unroll
  for (int kt = 0; kt < KTW_F; ++kt)
#pragma unroll
    for (int f = 0; f < 2; ++f)
#pragma unroll
      for (int j = 0; j < 4; ++j) {
        float x = acc[f][kt][j];
        if (x > tau[f][j]) {
          const int row = f * 16 + g * 4 + j;
          unsigned int s = atomicAdd(&cnt[row], 1u);
          if (s < CAP_F) {
            lidx[row][s] = wid * 128 + kt * 16 + col;
            lval[row][s] = x;
          }
        }
      }
  __syncthreads();

  for (int rr = 0; rr < 2; ++rr) {
    const int row = wid * 2 + rr;
    int n = (int)cnt[row]; if (n > CAP_F) n = CAP_F;
    float xv[4];
#pragma unroll
    for (int r = 0; r < 4; ++r) {
      const int i = lane + 64 * r;
      xv[r] = (i < n) ? lval[row][i] : -1e30f;
    }
    float tw = __shfl(tauRow, row);
    for (int it = 0; it < WMAXIT_F; ++it) {
      float s1 = 0.f, s2 = 0.f;
#pragma unroll
      for (int r = 0; r < 4; ++r) {
        float u = fmaxf(xv[r] - tw, 0.f);
        s1 += u; s2 = fmaf(u, u, s2);
      }
#pragma unroll
      for (int off = 1; off < 64; off <<= 1) {
        s1 += __shfl_xor(s1, off, 64);
        s2 += __shfl_xor(s2, off, 64);
      }
      float step = (s2 - 1.0f) / (2.0f * s1);
      tw += step;
      if (step < 1e-7f) break;
    }
#pragma unroll
    for (int r = 0; r < 4; ++r) {
      const int i = lane + 64 * r;
      if (i < n) {
        float u = fmaxf(xv[r] - tw, 0.f);
        lval[row][i] = u * u;
      }
    }
    float s = 0.f;
#pragma unroll 4
    for (int i = 0; i < n; ++i) {
      s = fmaf(lval[row][i], vp[(size_t)lidx[row][i] * D_ + lane], s);
    }
    op[row * D_ + lane] = s;
  }
}

extern "C" void kernel_launch(void* const* d_in, const int* in_sizes, int n_in,
                              void* d_out, int out_size, void* d_ws, size_t ws_size,
                              hipStream_t stream) {
  const float* q = (const float*)d_in[0];
  const float* k = (const float*)d_in[1];
  const float* v = (const float*)d_in[2];
  float* out = (float*)d_out;

  const size_t khi_b = (size_t)KELEMS * 2;                 // 4 MB each
  const size_t cnt_b = (size_t)NROWS * NSEG * 4;           // 2 MB
  const size_t tau_b = (size_t)NROWS * NSEG * 4;           // 2 MB
  const size_t base  = 2 * khi_b + cnt_b + tau_b;          // ~12.5 MB
  const size_t ent32 = (size_t)NROWS * NSEG * 32 * 4;      // 67 MB
  const size_t ent16 = (size_t)NROWS * NSEG * 16 * 4;      // 33.5 MB

  int cseg = 0;
  if (d_ws != nullptr) {
    if      (ws_size >= base + ent32) cseg = 32;           // ~80 MB
    else if (ws_size >= base + ent16) cseg = 16;           // ~46 MB
  }

  if (cseg != 0) {
    unsigned short* khi = (unsigned short*)d_ws;
    unsigned short* klo = khi + KELEMS;
    int*   gscnt = (int*)((char*)d_ws + 2 * khi_b);
    float* gstau = (float*)((char*)d_ws + 2 * khi_b + cnt_b);
    unsigned int* gent = (unsigned int*)((char*)d_ws + base);
    ksplit_kernel<<<dim3(KELEMS / (256 * 4)), dim3(256), 0, stream>>>(k, khi, klo);
    const dim3 gA(BH_ * 4 * (S_ / QT_A));
    const dim3 gB(NROWS / 4);
    if (cseg == 32) {
      entmax_scores_kernel<32><<<gA, dim3(256), 0, stream>>>(q, khi, klo, gscnt, gstau, gent);
      entmax_solvepv_kernel<32><<<gB, dim3(256), 0, stream>>>(q, k, v, gscnt, gstau, gent, out);
    } else {
      entmax_scores_kernel<16><<<gA, dim3(256), 0, stream>>>(q, khi, klo, gscnt, gstau, gent);
      entmax_solvepv_kernel<16><<<gB, dim3(256), 0, stream>>>(q, k, v, gscnt, gstau, gent, out);
    }
  } else if (d_ws != nullptr && ws_size >= 2 * khi_b) {
    unsigned short* khi = (unsigned short*)d_ws;
    unsigned short* klo = khi + KELEMS;
    ksplit_kernel<<<dim3(KELEMS / (256 * 4)), dim3(256), 0, stream>>>(k, khi, klo);
    entmax_attn_kernel<true><<<dim3(BH_ * (S_ / QT_F)), dim3(BLOCK_F), 0, stream>>>(
        q, k, khi, klo, v, out);
  } else {
    entmax_attn_kernel<false><<<dim3(BH_ * (S_ / QT_F)), dim3(BLOCK_F), 0, stream>>>(
        q, k, nullptr, nullptr, v, out);
  }
}

// Round 10
// 297.031 us; speedup vs baseline: 2.9868x; 1.0133x over previous
//
#include <hip/hip_runtime.h>
#include <math.h>

// Problem constants (B=2, H=8, S=2048, D=64)
#define BH_    16
#define S_     2048
#define D_     64
#define KELEMS (BH_ * S_ * D_)       // 2,097,152 K elements
#define NROWS  (BH_ * S_)            // 32,768 query rows
#define NSEG   16                    // wave-segments per row (4 kseg x 4 waves)

// ---- two-phase path geometry
#define SUPC   256      // support cap/row in phase B (true support ~20-60;
                        // R5 empirically bounded candidates-at-threshold <=256)
#define QT_A   16       // queries per phase-A block (MFMA M)
#define KTW_A  8        // 16-key tiles per wave (128 keys/wave, 4 waves)
#define ITW_A  5        // fixed wave-subset Newton iterations
#define BMAXIT 32       // phase-B Newton max iterations (early-exit)

// ---- fallback (R5 single-kernel) geometry
#define QT_F    32
#define BLOCK_F 1024
#define NW_F    16
#define KTW_F   8
#define CAP_F   256
#define ITPRE_F 5
#define WMAXIT_F 16

typedef __attribute__((ext_vector_type(8))) short bf16x8;   // 8 bf16 = 4 VGPR
typedef __attribute__((ext_vector_type(4))) float f32x4;

// Exact hi/lo bf16 truncation split of 8 consecutive floats.
// x = hi + lo + eps, |eps| <= 2^-15 |x|; products use hh + hl + lh (drop ll).
__device__ __forceinline__ void split8(const float4 f0, const float4 f1,
                                       bf16x8& hi, bf16x8& lo) {
  union { bf16x8 v; unsigned int u[4]; } H, L;
  const float ff[8] = {f0.x, f0.y, f0.z, f0.w, f1.x, f1.y, f1.z, f1.w};
#pragma unroll
  for (int p = 0; p < 4; ++p) {
    unsigned int b0 = __float_as_uint(ff[2 * p]);
    unsigned int b1 = __float_as_uint(ff[2 * p + 1]);
    unsigned int h0 = b0 & 0xFFFF0000u;
    unsigned int h1 = b1 & 0xFFFF0000u;
    H.u[p] = (h0 >> 16) | h1;                       // lo short = elem 2p
    float l0 = ff[2 * p]     - __uint_as_float(h0); // exact in fp32
    float l1 = ff[2 * p + 1] - __uint_as_float(h1);
    L.u[p] = (__float_as_uint(l0) >> 16) | (__float_as_uint(l1) & 0xFFFF0000u);
  }
  hi = H.v; lo = L.v;
}

// Prepass: K fp32 -> (Khi, Klo) bf16 (same element order).
__global__ __launch_bounds__(256)
void ksplit_kernel(const float* __restrict__ k,
                   unsigned short* __restrict__ khi,
                   unsigned short* __restrict__ klo) {
  const int i = (blockIdx.x * 256 + threadIdx.x) * 4;
  float4 x = *(const float4*)(k + i);
  ushort4 h, l;
  {
    unsigned int b;
    b = __float_as_uint(x.x); h.x = (unsigned short)(b >> 16);
    l.x = (unsigned short)(__float_as_uint(x.x - __uint_as_float(b & 0xFFFF0000u)) >> 16);
    b = __float_as_uint(x.y); h.y = (unsigned short)(b >> 16);
    l.y = (unsigned short)(__float_as_uint(x.y - __uint_as_float(b & 0xFFFF0000u)) >> 16);
    b = __float_as_uint(x.z); h.z = (unsigned short)(b >> 16);
    l.z = (unsigned short)(__float_as_uint(x.z - __uint_as_float(b & 0xFFFF0000u)) >> 16);
    b = __float_as_uint(x.w); h.w = (unsigned short)(b >> 16);
    l.w = (unsigned short)(__float_as_uint(x.w - __uint_as_float(b & 0xFFFF0000u)) >> 16);
  }
  *(ushort4*)(khi + i) = h;
  *(ushort4*)(klo + i) = l;
}

// ============ Phase A: MFMA scores + ATOMIC-FREE wave compaction ============
// Block = 16 q x 512 keys; wave owns 128 keys (segment seg = kseg*4+wave).
// Wave-subset Newton from below: every iterate tau_w <= subset root <= tau*,
// so admitting {x > tau_w} keeps the full support for ANY data. Slot
// assignment is ballot+popcount (R7: global atomicAdd chain was ~680us).
// Entry = fp32 score with low 11 mantissa bits replaced by key index.
// Meta (count, tau) packed into one int2 per (row, segment).
template <int CSEG>
__global__ __launch_bounds__(256, 5)
void entmax_scores_kernel(const float* __restrict__ q,
                          const unsigned short* __restrict__ khi,
                          const unsigned short* __restrict__ klo,
                          int2* __restrict__ gmeta,
                          unsigned int* __restrict__ gent) {
  const int t    = threadIdx.x;
  const int wave = t >> 6;
  const int lane = t & 63;
  const int g    = lane >> 4;
  const int col  = lane & 15;

  // head-XCD affinity: bh = blk & 15 -> blk % 8 == bh % 8 under round-robin.
  const int blk  = blockIdx.x;
  const int bh   = blk & 15;
  const int kseg = (blk >> 4) & 3;
  const int qt   = blk >> 6;                   // 0..127
  const float* qp = q + ((size_t)bh * S_ + (size_t)qt * QT_A) * D_;

  // Q fragment: A row = col, d = ks*32 + g*8 + i; fold scale/2 => *1/16.
  bf16x8 qh[2], ql[2];
#pragma unroll
  for (int ks = 0; ks < 2; ++ks) {
    const float* src = qp + col * D_ + ks * 32 + g * 8;
    float4 f0 = *(const float4*)src;
    float4 f1 = *(const float4*)(src + 4);
    f0.x *= 0.0625f; f0.y *= 0.0625f; f0.z *= 0.0625f; f0.w *= 0.0625f;
    f1.x *= 0.0625f; f1.y *= 0.0625f; f1.z *= 0.0625f; f1.w *= 0.0625f;
    split8(f0, f1, qh[ks], ql[ks]);
  }

  // QK^T over this wave's 128 keys: acc[kt][j] = x[row=g*4+j][kbase+kt*16+col]
  const int kbase = kseg * 512 + wave * 128;
  f32x4 acc[KTW_A];
#pragma unroll
  for (int kt = 0; kt < KTW_A; ++kt) acc[kt] = (f32x4){0.f, 0.f, 0.f, 0.f};
#pragma unroll
  for (int kt = 0; kt < KTW_A; ++kt) {
    const size_t rowoff = ((size_t)bh * S_ + kbase + kt * 16 + col) * D_;
#pragma unroll
    for (int ks = 0; ks < 2; ++ks) {
      bf16x8 kh = *(const bf16x8*)(khi + rowoff + ks * 32 + g * 8);
      bf16x8 kl = *(const bf16x8*)(klo + rowoff + ks * 32 + g * 8);
      acc[kt] = __builtin_amdgcn_mfma_f32_16x16x32_bf16(qh[ks], kh, acc[kt], 0, 0, 0);
      acc[kt] = __builtin_amdgcn_mfma_f32_16x16x32_bf16(qh[ks], kl, acc[kt], 0, 0, 0);
      acc[kt] = __builtin_amdgcn_mfma_f32_16x16x32_bf16(ql[ks], kh, acc[kt], 0, 0, 0);
    }
  }

  // Wave-local row max over its 128 keys (16-lane col-group butterfly).
  float m4[4];
#pragma unroll
  for (int j = 0; j < 4; ++j) {
    float mm = acc[0][j];
#pragma unroll
    for (int kt = 1; kt < KTW_A; ++kt) mm = fmaxf(mm, acc[kt][j]);
    m4[j] = mm;
  }
#pragma unroll
  for (int off = 1; off < 16; off <<= 1)
#pragma unroll
    for (int j = 0; j < 4; ++j) m4[j] = fmaxf(m4[j], __shfl_xor(m4[j], off, 64));

  // Wave-subset Newton from tau0 = m_w - 1; s2 >= 1 -> s1 >= 1 below the
  // subset root, so the division is safe. Fixed ITW_A iterations.
  float tau[4];
#pragma unroll
  for (int j = 0; j < 4; ++j) tau[j] = m4[j] - 1.0f;
  for (int it = 0; it < ITW_A; ++it) {
    float s1[4] = {0, 0, 0, 0}, s2[4] = {0, 0, 0, 0};
#pragma unroll
    for (int kt = 0; kt < KTW_A; ++kt)
#pragma unroll
      for (int j = 0; j < 4; ++j) {
        float u = fmaxf(acc[kt][j] - tau[j], 0.f);
        s1[j] += u; s2[j] = fmaf(u, u, s2[j]);
      }
#pragma unroll
    for (int off = 1; off < 16; off <<= 1)
#pragma unroll
      for (int j = 0; j < 4; ++j) {
        s1[j] += __shfl_xor(s1[j], off, 64);
        s2[j] += __shfl_xor(s2[j], off, 64);
      }
#pragma unroll
    for (int j = 0; j < 4; ++j) tau[j] += (s2[j] - 1.0f) / (2.0f * s1[j]);
  }

  // Atomic-free compaction: one ballot per (kt,j); slot = prefix popcount
  // within the row's 16-lane group. True (un-clamped) counts + taus written
  // once per group as int2: overflow detection AND the phase-B warm start.
  const int seg = kseg * 4 + wave;
  int base[4] = {0, 0, 0, 0};
#pragma unroll
  for (int kt = 0; kt < KTW_A; ++kt) {
#pragma unroll
    for (int j = 0; j < 4; ++j) {
      const bool pred = acc[kt][j] > tau[j];
      const unsigned long long mb = __ballot(pred);
      const unsigned int field = (unsigned int)(mb >> (g * 16)) & 0xFFFFu;
      if (pred) {
        const int slot = base[j] + __popc(field & ((1u << col) - 1u));
        if (slot < CSEG) {
          const int rowg = bh * S_ + qt * QT_A + g * 4 + j;
          const unsigned int key = (unsigned int)(kbase + kt * 16 + col);
          const unsigned int e = (__float_as_uint(acc[kt][j]) & 0xFFFFF800u) | key;
          gent[(size_t)rowg * (NSEG * CSEG) + seg * CSEG + slot] = e;
        }
      }
      base[j] += __popc(field);
    }
  }
  if (col == 0) {
#pragma unroll
    for (int j = 0; j < 4; ++j) {
      const size_t o = (size_t)(bh * S_ + qt * QT_A + g * 4 + j) * NSEG + seg;
      gmeta[o] = make_int2(base[j], __float_as_int(tau[j]));
    }
  }
}

// ============ Phase B: exact per-row Newton + sparse PV ============
// One wave per row. R10: the three shared fixed costs of R8/R9 removed:
// (1) gent read = 2x uint4 per lane (each lane's 4 slots stay inside one
//     32-slot segment: sg = r2*8 + (lane>>3), two shuffles total);
// (2) support compaction via ballot-prefix (was ~30 serialized same-address
//     LDS atomics per wave);
// (3) meta = one int2 load (count, tau) instead of two dependent loads.
// Warm start tau0 = max of the 16 published segment roots (each <= tau*).
// Overflow (any segment count > CSEG): exact full-row fp32 recompute.
template <int CSEG>
__global__ __launch_bounds__(256)
void entmax_solvepv_kernel(const float* __restrict__ q,
                           const float* __restrict__ k,
                           const float* __restrict__ v,
                           const int2* __restrict__ gmeta,
                           const unsigned int* __restrict__ gent,
                           float* __restrict__ out) {
  constexpr int NSLOT = NSEG * CSEG;           // 512
  constexpr int NR    = NSLOT / 64;            // 8 regs per lane
  constexpr int NV    = NR / 4;                // 2 uint4 loads per lane
  __shared__ int   sidx[4][SUPC];
  __shared__ float sp[4][SUPC];
  __shared__ float qs[4][D_];

  const int t    = threadIdx.x;
  const int wid  = t >> 6;
  const int lane = t & 63;
  const int blk  = blockIdx.x;
  const int bh   = blk & 15;                   // head-XCD affinity for V
  const int u    = blk >> 4;                   // 0..511
  const int rowg = bh * S_ + u * 4 + wid;
  const float* vp = v + (size_t)bh * S_ * D_;

  // meta: one int2 per segment (count, tau-bits), lanes 0-15.
  int cw = 0; float tw = -3e38f;
  if (lane < NSEG) {
    const int2 m = gmeta[(size_t)rowg * NSEG + lane];
    cw = m.x; tw = __int_as_float(m.y);
  }
  const bool ovf = __ballot(cw > CSEG) != 0ull;
  int sn = 0;

  if (!ovf) {
    // warm start: max of the 16 segment taus.
    float ts = tw;
#pragma unroll
    for (int off = 1; off < 64; off <<= 1) ts = fmaxf(ts, __shfl_xor(ts, off, 64));
    float tau = ts;

    // vectorized padded load: slot = r2*256 + lane*4 + c (one segment per
    // lane per r2 since 4 | 32).
    float xv[NR]; int iv[NR];
    const uint4* gbase = (const uint4*)(gent + (size_t)rowg * NSLOT);
#pragma unroll
    for (int r2 = 0; r2 < NV; ++r2) {
      const uint4 e4 = gbase[r2 * 64 + lane];
      const int cs  = __shfl(cw, r2 * 8 + (lane >> 3));
      const int ii0 = (lane * 4) & (CSEG - 1);
      const unsigned int es[4] = {e4.x, e4.y, e4.z, e4.w};
#pragma unroll
      for (int c = 0; c < 4; ++c) {
        const bool valid = (ii0 + c) < cs;
        xv[r2 * 4 + c] = valid ? __uint_as_float(es[c] & 0xFFFFF800u) : -1e30f;
        iv[r2 * 4 + c] = (int)(es[c] & 0x7FFu);
      }
    }

    for (int it = 0; it < BMAXIT; ++it) {
      float s1 = 0.f, s2 = 0.f;
#pragma unroll
      for (int r = 0; r < NR; ++r) {
        float uu = fmaxf(xv[r] - tau, 0.f);
        s1 += uu; s2 = fmaf(uu, uu, s2);
      }
#pragma unroll
      for (int off = 1; off < 64; off <<= 1) {
        s1 += __shfl_xor(s1, off, 64);
        s2 += __shfl_xor(s2, off, 64);
      }
      float step = (s2 - 1.0f) / (2.0f * s1);  // s1 >= 1 below the root
      tau += step;
      if (step < 1e-7f) break;                 // lane-uniform
    }

    // ballot-prefix support compaction (no LDS atomics; sn wave-uniform).
#pragma unroll
    for (int r = 0; r < NR; ++r) {
      const float uu = xv[r] - tau;
      const bool pred = uu > 0.f;
      const unsigned long long mb = __ballot(pred);
      if (pred) {
        const int slot = sn + __popcll(mb & ((1ull << lane) - 1ull));
        if (slot < SUPC) { sidx[wid][slot] = iv[r]; sp[wid][slot] = uu * uu; }
      }
      sn += (int)__popcll(mb);
    }
  } else {
    // ---- overflow repair: exact fp32 recompute of this row (32 keys/lane).
    qs[wid][lane] = q[(size_t)rowg * D_ + lane] * 0.0625f;
    const float* kb = k + (size_t)bh * S_ * D_;
    float xs[32];
    for (int r = 0; r < 32; ++r) {
      const float* krow = kb + (size_t)(lane + (r << 6)) * D_;
      float d = 0.f;
#pragma unroll 4
      for (int dc = 0; dc < D_; dc += 4) {
        float4 kv4 = *(const float4*)(krow + dc);
        d = fmaf(qs[wid][dc + 0], kv4.x, d);
        d = fmaf(qs[wid][dc + 1], kv4.y, d);
        d = fmaf(qs[wid][dc + 2], kv4.z, d);
        d = fmaf(qs[wid][dc + 3], kv4.w, d);
      }
      xs[r] = d;
    }
    float mx = xs[0];
#pragma unroll
    for (int r = 1; r < 32; ++r) mx = fmaxf(mx, xs[r]);
#pragma unroll
    for (int off = 1; off < 64; off <<= 1) mx = fmaxf(mx, __shfl_xor(mx, off, 64));
    float tau = mx - 1.0f;
    for (int it = 0; it < BMAXIT; ++it) {
      float s1 = 0.f, s2 = 0.f;
#pragma unroll
      for (int r = 0; r < 32; ++r) {
        float uu = fmaxf(xs[r] - tau, 0.f);
        s1 += uu; s2 = fmaf(uu, uu, s2);
      }
#pragma unroll
      for (int off = 1; off < 64; off <<= 1) {
        s1 += __shfl_xor(s1, off, 64);
        s2 += __shfl_xor(s2, off, 64);
      }
      float step = (s2 - 1.0f) / (2.0f * s1);
      tau += step;
      if (step < 1e-7f) break;
    }
#pragma unroll
    for (int r = 0; r < 32; ++r) {
      const float uu = xs[r] - tau;
      const bool pred = uu > 0.f;
      const unsigned long long mb = __ballot(pred);
      if (pred) {
        const int slot = sn + __popcll(mb & ((1ull << lane) - 1ull));
        if (slot < SUPC) { sidx[wid][slot] = lane + (r << 6); sp[wid][slot] = uu * uu; }
      }
      sn += (int)__popcll(mb);
    }
  }

  if (sn > SUPC) sn = SUPC;

  // ---- parallel PV: entry subgroup eg = lane>>4 (stride-4 over support),
  // d-column d4 = lane&15 (float4). 4 independent LDS->V chains; 2-level
  // float4 butterfly; lanes 0-15 write the row.
  const int eg = lane >> 4;
  const int d4 = lane & 15;
  float4 a4 = {0.f, 0.f, 0.f, 0.f};
  for (int i = eg; i < sn; i += 4) {
    const float pv = sp[wid][i];               // broadcast within the group
    const float4 vv = *(const float4*)&vp[(size_t)sidx[wid][i] * D_ + d4 * 4];
    a4.x = fmaf(pv, vv.x, a4.x); a4.y = fmaf(pv, vv.y, a4.y);
    a4.z = fmaf(pv, vv.z, a4.z); a4.w = fmaf(pv, vv.w, a4.w);
  }
#pragma unroll
  for (int off = 16; off < 64; off <<= 1) {
    a4.x += __shfl_xor(a4.x, off, 64);
    a4.y += __shfl_xor(a4.y, off, 64);
    a4.z += __shfl_xor(a4.z, off, 64);
    a4.w += __shfl_xor(a4.w, off, 64);
  }
  if (lane < 16)
    *(float4*)&out[(size_t)rowg * D_ + d4 * 4] = a4;
}

// ============ Fallback: R5 single-kernel path (verbatim) ============
template <bool PRE>
__global__ __launch_bounds__(BLOCK_F, 4)
void entmax_attn_kernel(const float* __restrict__ q,
                        const float* __restrict__ k,
                        const unsigned short* __restrict__ khi,
                        const unsigned short* __restrict__ klo,
                        const float* __restrict__ v,
                        float* __restrict__ out) {
  __shared__ float redM[NW_F][QT_F];
  __shared__ float redS1[2][NW_F][QT_F];
  __shared__ float redS2[2][NW_F][QT_F];
  __shared__ unsigned int cnt[QT_F];
  __shared__ int   lidx[QT_F][CAP_F];
  __shared__ float lval[QT_F][CAP_F];

  const int t    = threadIdx.x;
  const int wid  = t >> 6;
  const int lane = t & 63;
  const int g    = lane >> 4;
  const int col  = lane & 15;
  const int rowL = lane & 31;

  const int blk = blockIdx.x;
  const int bh  = blk & 15;
  const int qt  = blk >> 4;
  const float* qp = q + ((size_t)bh * S_ + (size_t)qt * QT_F) * D_;
  const float* kp = k + (size_t)bh * S_ * D_;
  const float* vp = v + (size_t)bh * S_ * D_;
  float* op = out + ((size_t)bh * S_ + (size_t)qt * QT_F) * D_;

  if (t < QT_F) cnt[t] = 0;

  bf16x8 qh[2][2], ql[2][2];
#pragma unroll
  for (int f = 0; f < 2; ++f)
#pragma unroll
    for (int ks = 0; ks < 2; ++ks) {
      const float* src = qp + (f * 16 + col) * D_ + ks * 32 + g * 8;
      float4 f0 = *(const float4*)src;
      float4 f1 = *(const float4*)(src + 4);
      f0.x *= 0.0625f; f0.y *= 0.0625f; f0.z *= 0.0625f; f0.w *= 0.0625f;
      f1.x *= 0.0625f; f1.y *= 0.0625f; f1.z *= 0.0625f; f1.w *= 0.0625f;
      split8(f0, f1, qh[f][ks], ql[f][ks]);
    }

  f32x4 acc[2][KTW_F];
#pragma unroll
  for (int f = 0; f < 2; ++f)
#pragma unroll
    for (int kt = 0; kt < KTW_F; ++kt) acc[f][kt] = (f32x4){0.f, 0.f, 0.f, 0.f};
#pragma unroll
  for (int kt = 0; kt < KTW_F; ++kt) {
    const size_t rowoff = (size_t)(wid * 128 + kt * 16 + col) * D_;
#pragma unroll
    for (int ks = 0; ks < 2; ++ks) {
      bf16x8 kh, kl;
      if (PRE) {
        const size_t eoff = (size_t)bh * S_ * D_ + rowoff + ks * 32 + g * 8;
        kh = *(const bf16x8*)(khi + eoff);
        kl = *(const bf16x8*)(klo + eoff);
      } else {
        const float* src = kp + rowoff + ks * 32 + g * 8;
        split8(*(const float4*)src, *(const float4*)(src + 4), kh, kl);
      }
#pragma unroll
      for (int f = 0; f < 2; ++f) {
        acc[f][kt] = __builtin_amdgcn_mfma_f32_16x16x32_bf16(qh[f][ks], kh, acc[f][kt], 0, 0, 0);
        acc[f][kt] = __builtin_amdgcn_mfma_f32_16x16x32_bf16(qh[f][ks], kl, acc[f][kt], 0, 0, 0);
        acc[f][kt] = __builtin_amdgcn_mfma_f32_16x16x32_bf16(ql[f][ks], kh, acc[f][kt], 0, 0, 0);
      }
    }
  }

  {
    float m4[2][4];
#pragma unroll
    for (int f = 0; f < 2; ++f)
#pragma unroll
      for (int j = 0; j < 4; ++j) {
        float mm = acc[f][0][j];
#pragma unroll
        for (int kt = 1; kt < KTW_F; ++kt) mm = fmaxf(mm, acc[f][kt][j]);
        m4[f][j] = mm;
      }
#pragma unroll
    for (int off = 1; off < 16; off <<= 1)
#pragma unroll
      for (int f = 0; f < 2; ++f)
#pragma unroll
        for (int j = 0; j < 4; ++j)
          m4[f][j] = fmaxf(m4[f][j], __shfl_xor(m4[f][j], off, 64));
    if (col == 0) {
#pragma unroll
      for (int f = 0; f < 2; ++f)
#pragma unroll
        for (int j = 0; j < 4; ++j) redM[wid][f * 16 + g * 4 + j] = m4[f][j];
    }
  }
  __syncthreads();

  float tauRow;
  {
    float mm = redM[0][rowL];
#pragma unroll
    for (int w = 1; w < NW_F; ++w) mm = fmaxf(mm, redM[w][rowL]);
    tauRow = mm - 1.0f;
  }
  float tau[2][4];
#pragma unroll
  for (int f = 0; f < 2; ++f)
#pragma unroll
    for (int j = 0; j < 4; ++j) tau[f][j] = __shfl(tauRow, f * 16 + g * 4 + j);

  for (int it = 0; it < ITPRE_F; ++it) {
    const int b = it & 1;
    float s1[2][4] = {{0,0,0,0},{0,0,0,0}}, s2[2][4] = {{0,0,0,0},{0,0,0,0}};
#pragma unroll
    for (int kt = 0; kt < KTW_F; ++kt)
#pragma unroll
      for (int f = 0; f < 2; ++f)
#pragma unroll
        for (int j = 0; j < 4; ++j) {
          float u = fmaxf(acc[f][kt][j] - tau[f][j], 0.f);
          s1[f][j] += u; s2[f][j] = fmaf(u, u, s2[f][j]);
        }
#pragma unroll
    for (int off = 1; off < 16; off <<= 1)
#pragma unroll
      for (int f = 0; f < 2; ++f)
#pragma unroll
        for (int j = 0; j < 4; ++j) {
          s1[f][j] += __shfl_xor(s1[f][j], off, 64);
          s2[f][j] += __shfl_xor(s2[f][j], off, 64);
        }
    if (col == 0) {
#pragma unroll
      for (int f = 0; f < 2; ++f)
#pragma unroll
        for (int j = 0; j < 4; ++j) {
          redS1[b][wid][f * 16 + g * 4 + j] = s1[f][j];
          redS2[b][wid][f * 16 + g * 4 + j] = s2[f][j];
        }
    }
    __syncthreads();
    const float* pS = (lane < 32) ? &redS1[b][0][rowL] : &redS2[b][0][rowL];
    float T = 0.f;
#pragma unroll
    for (int w = 0; w < NW_F; ++w) T += pS[w * QT_F];
    float other = __shfl_xor(T, 32, 64);
    float step_r = (other - 1.0f) / (2.0f * T);
    if (lane < 32) tauRow += step_r;
#pragma unroll
    for (int f = 0; f < 2; ++f)
#pragma unroll
      for (int j = 0; j < 4; ++j)
        tau[f][j] += __shfl(step_r, f * 16 + g * 4 + j);
  }

#pragma unroll
  for (int kt = 0; kt < KTW_F; ++kt)
#pragma unroll
    for (int f = 0; f < 2; ++f)
#pragma unroll
      for (int j = 0; j < 4; ++j) {
        float x = acc[f][kt][j];
        if (x > tau[f][j]) {
          const int row = f * 16 + g * 4 + j;
          unsigned int s = atomicAdd(&cnt[row], 1u);
          if (s < CAP_F) {
            lidx[row][s] = wid * 128 + kt * 16 + col;
            lval[row][s] = x;
          }
        }
      }
  __syncthreads();

  for (int rr = 0; rr < 2; ++rr) {
    const int row = wid * 2 + rr;
    int n = (int)cnt[row]; if (n > CAP_F) n = CAP_F;
    float xv[4];
#pragma unroll
    for (int r = 0; r < 4; ++r) {
      const int i = lane + 64 * r;
      xv[r] = (i < n) ? lval[row][i] : -1e30f;
    }
    float tw = __shfl(tauRow, row);
    for (int it = 0; it < WMAXIT_F; ++it) {
      float s1 = 0.f, s2 = 0.f;
#pragma unroll
      for (int r = 0; r < 4; ++r) {
        float u = fmaxf(xv[r] - tw, 0.f);
        s1 += u; s2 = fmaf(u, u, s2);
      }
#pragma unroll
      for (int off = 1; off < 64; off <<= 1) {
        s1 += __shfl_xor(s1, off, 64);
        s2 += __shfl_xor(s2, off, 64);
      }
      float step = (s2 - 1.0f) / (2.0f * s1);
      tw += step;
      if (step < 1e-7f) break;
    }
#pragma unroll
    for (int r = 0; r < 4; ++r) {
      const int i = lane + 64 * r;
      if (i < n) {
        float u = fmaxf(xv[r] - tw, 0.f);
        lval[row][i] = u * u;
      }
    }
    float s = 0.f;
#pragma unroll 4
    for (int i = 0; i < n; ++i) {
      s = fmaf(lval[row][i], vp[(size_t)lidx[row][i] * D_ + lane], s);
    }
    op[row * D_ + lane] = s;
  }
}

extern "C" void kernel_launch(void* const* d_in, const int* in_sizes, int n_in,
                              void* d_out, int out_size, void* d_ws, size_t ws_size,
                              hipStream_t stream) {
  const float* q = (const float*)d_in[0];
  const float* k = (const float*)d_in[1];
  const float* v = (const float*)d_in[2];
  float* out = (float*)d_out;

  const size_t khi_b  = (size_t)KELEMS * 2;                // 4 MB each
  const size_t meta_b = (size_t)NROWS * NSEG * 8;          // 4 MB
  const size_t base   = 2 * khi_b + meta_b;                // ~12.5 MB
  const size_t ent32  = (size_t)NROWS * NSEG * 32 * 4;     // 67 MB

  if (d_ws != nullptr && ws_size >= base + ent32) {        // ~80 MB (R9 fit)
    unsigned short* khi = (unsigned short*)d_ws;
    unsigned short* klo = khi + KELEMS;
    int2* gmeta = (int2*)((char*)d_ws + 2 * khi_b);
    unsigned int* gent = (unsigned int*)((char*)d_ws + base);
    ksplit_kernel<<<dim3(KELEMS / (256 * 4)), dim3(256), 0, stream>>>(k, khi, klo);
    entmax_scores_kernel<32><<<dim3(BH_ * 4 * (S_ / QT_A)), dim3(256), 0, stream>>>(
        q, khi, klo, gmeta, gent);
    entmax_solvepv_kernel<32><<<dim3(NROWS / 4), dim3(256), 0, stream>>>(
        q, k, v, gmeta, gent, out);
  } else if (d_ws != nullptr && ws_size >= 2 * khi_b) {
    unsigned short* khi = (unsigned short*)d_ws;
    unsigned short* klo = khi + KELEMS;
    ksplit_kernel<<<dim3(KELEMS / (256 * 4)), dim3(256), 0, stream>>>(k, khi, klo);
    entmax_attn_kernel<true><<<dim3(BH_ * (S_ / QT_F)), dim3(BLOCK_F), 0, stream>>>(
        q, k, khi, klo, v, out);
  } else {
    entmax_attn_kernel<false><<<dim3(BH_ * (S_ / QT_F)), dim3(BLOCK_F), 0, stream>>>(
        q, k, nullptr, nullptr, v, out);
  }
}

// Round 11
// 290.147 us; speedup vs baseline: 3.0577x; 1.0237x over previous
//
#include <hip/hip_runtime.h>
#include <math.h>

// Problem constants (B=2, H=8, S=2048, D=64)
#define BH_    16
#define S_     2048
#define D_     64
#define KELEMS (BH_ * S_ * D_)   // 2,097,152 K elements
#define QT     32                // queries per block (2 MFMA A-frags per wave)
#define BLOCK  1024              // 16 waves
#define NW     16
#define KTW    8                 // 16x16 C-tiles per wave: 128 keys/wave
#define CAP    320               // per-row candidate cap (R9: avg ~126/row at
                                 // 5-iter segment tau; overflow -> exact repair)
#define ITW    5                 // wave-segment Newton iterations (fixed)
#define WMAXIT 24                // exact row Newton max iters (early-exit)

typedef __attribute__((ext_vector_type(8))) short bf16x8;   // 8 bf16 = 4 VGPR
typedef __attribute__((ext_vector_type(4))) float f32x4;

// Exact hi/lo bf16 truncation split of 8 consecutive floats.
// x = hi + lo + eps, |eps| <= 2^-15 |x|; products use hh + hl + lh (drop ll).
__device__ __forceinline__ void split8(const float4 f0, const float4 f1,
                                       bf16x8& hi, bf16x8& lo) {
  union { bf16x8 v; unsigned int u[4]; } H, L;
  const float ff[8] = {f0.x, f0.y, f0.z, f0.w, f1.x, f1.y, f1.z, f1.w};
#pragma unroll
  for (int p = 0; p < 4; ++p) {
    unsigned int b0 = __float_as_uint(ff[2 * p]);
    unsigned int b1 = __float_as_uint(ff[2 * p + 1]);
    unsigned int h0 = b0 & 0xFFFF0000u;
    unsigned int h1 = b1 & 0xFFFF0000u;
    H.u[p] = (h0 >> 16) | h1;                       // lo short = elem 2p
    float l0 = ff[2 * p]     - __uint_as_float(h0); // exact in fp32
    float l1 = ff[2 * p + 1] - __uint_as_float(h1);
    L.u[p] = (__float_as_uint(l0) >> 16) | (__float_as_uint(l1) & 0xFFFF0000u);
  }
  hi = H.v; lo = L.v;
}

// Prepass: K fp32 -> (Khi, Klo) bf16, same element order.
__global__ __launch_bounds__(256)
void ksplit_kernel(const float* __restrict__ k,
                   unsigned short* __restrict__ khi,
                   unsigned short* __restrict__ klo) {
  const int i = (blockIdx.x * 256 + threadIdx.x) * 4;
  float4 x = *(const float4*)(k + i);
  ushort4 h, l;
  {
    unsigned int b;
    b = __float_as_uint(x.x); h.x = (unsigned short)(b >> 16);
    l.x = (unsigned short)(__float_as_uint(x.x - __uint_as_float(b & 0xFFFF0000u)) >> 16);
    b = __float_as_uint(x.y); h.y = (unsigned short)(b >> 16);
    l.y = (unsigned short)(__float_as_uint(x.y - __uint_as_float(b & 0xFFFF0000u)) >> 16);
    b = __float_as_uint(x.z); h.z = (unsigned short)(b >> 16);
    l.z = (unsigned short)(__float_as_uint(x.z - __uint_as_float(b & 0xFFFF0000u)) >> 16);
    b = __float_as_uint(x.w); h.w = (unsigned short)(b >> 16);
    l.w = (unsigned short)(__float_as_uint(x.w - __uint_as_float(b & 0xFFFF0000u)) >> 16);
  }
  *(ushort4*)(khi + i) = h;
  *(ushort4*)(klo + i) = l;
}

// ============ Single-pass kernel: R5 skeleton + R8/R9/R10 upgrades ============
// Block = 32 q x 2048 keys, 16 waves; wave wid owns keys [wid*128, wid*128+128).
// Pipeline: MFMA scores -> WAVE-LOCAL segment Newton (5 iters, ZERO barriers;
// every iterate tau_w <= subset root <= tau*) -> per-candidate LDS compaction
// -> barrier -> per-row exact Newton warm-started at max(segment taus) ->
// in-place ballot support compaction -> 4-way parallel PV.
// Exactness is repair-backed: a row whose true count exceeds CAP is recomputed
// from fp32 K by its owning wave (rare; R9 measured avg ~126 candidates/row).
template <bool PRE>
__global__ __launch_bounds__(BLOCK, 4)   // acc=64 AGPR -> 4 waves/SIMD
void entmax_attn_kernel(const float* __restrict__ q,
                        const float* __restrict__ k,
                        const unsigned short* __restrict__ khi,
                        const unsigned short* __restrict__ klo,
                        const float* __restrict__ v,
                        float* __restrict__ out) {
  __shared__ unsigned int cnt[QT];     // TRUE candidate counts (un-clamped)
  __shared__ float stau[QT][NW];       // per-(row, segment) Newton-5 tau
  __shared__ int   lidx[QT][CAP];      // candidates: key index  (40 KB)
  __shared__ float lval[QT][CAP];      // candidates: x, then p  (40 KB)
  __shared__ float qsR[NW][D_];        // repair-path q rows (4 KB)

  const int t    = threadIdx.x;
  const int wid  = t >> 6;             // 0..15 (= key segment)
  const int lane = t & 63;
  const int g    = lane >> 4;          // lane group 0..3
  const int col  = lane & 15;          // MFMA col (key) / A-row index

  // head-XCD affinity: bh = blk & 15 -> blk % 8 == bh % 8 under round-robin.
  const int blk = blockIdx.x;
  const int bh  = blk & 15;
  const int qt  = blk >> 4;            // 0..63
  const float* qp = q + ((size_t)bh * S_ + (size_t)qt * QT) * D_;
  const float* kp = k + (size_t)bh * S_ * D_;
  const float* vp = v + (size_t)bh * S_ * D_;
  float* op = out + ((size_t)bh * S_ + (size_t)qt * QT) * D_;

  if (t < QT) cnt[t] = 0;

  // ---- Q fragments: A-frag f covers rows f*16..f*16+15 (row = col).
  // Fold scale (1/8) and entmax /2 => *1/16 (power of 2: exact prescale).
  bf16x8 qh[2][2], ql[2][2];
#pragma unroll
  for (int f = 0; f < 2; ++f)
#pragma unroll
    for (int ks = 0; ks < 2; ++ks) {
      const float* src = qp + (f * 16 + col) * D_ + ks * 32 + g * 8;
      float4 f0 = *(const float4*)src;
      float4 f1 = *(const float4*)(src + 4);
      f0.x *= 0.0625f; f0.y *= 0.0625f; f0.z *= 0.0625f; f0.w *= 0.0625f;
      f1.x *= 0.0625f; f1.y *= 0.0625f; f1.z *= 0.0625f; f1.w *= 0.0625f;
      split8(f0, f1, qh[f][ks], ql[f][ks]);
    }

  // ---- QK^T: acc[f][kt][j] = x[row=f*16+g*4+j][key=wid*128+kt*16+col].
  // fp32-ish accuracy: qh*kh + qh*kl + ql*kh (drop ll, ~2^-15 rel).
  f32x4 acc[2][KTW];
#pragma unroll
  for (int f = 0; f < 2; ++f)
#pragma unroll
    for (int kt = 0; kt < KTW; ++kt) acc[f][kt] = (f32x4){0.f, 0.f, 0.f, 0.f};
#pragma unroll
  for (int kt = 0; kt < KTW; ++kt) {
    const size_t rowoff = (size_t)(wid * 128 + kt * 16 + col) * D_;
#pragma unroll
    for (int ks = 0; ks < 2; ++ks) {
      bf16x8 kh, kl;
      if (PRE) {
        const size_t eoff = (size_t)bh * S_ * D_ + rowoff + ks * 32 + g * 8;
        kh = *(const bf16x8*)(khi + eoff);
        kl = *(const bf16x8*)(klo + eoff);
      } else {
        const float* src = kp + rowoff + ks * 32 + g * 8;
        split8(*(const float4*)src, *(const float4*)(src + 4), kh, kl);
      }
#pragma unroll
      for (int f = 0; f < 2; ++f) {
        acc[f][kt] = __builtin_amdgcn_mfma_f32_16x16x32_bf16(qh[f][ks], kh, acc[f][kt], 0, 0, 0);
        acc[f][kt] = __builtin_amdgcn_mfma_f32_16x16x32_bf16(qh[f][ks], kl, acc[f][kt], 0, 0, 0);
        acc[f][kt] = __builtin_amdgcn_mfma_f32_16x16x32_bf16(ql[f][ks], kh, acc[f][kt], 0, 0, 0);
      }
    }
  }

  // ---- wave-segment row max over this wave's 128 keys (16-lane butterfly).
  float m4[2][4];
#pragma unroll
  for (int f = 0; f < 2; ++f)
#pragma unroll
    for (int j = 0; j < 4; ++j) {
      float mm = acc[f][0][j];
#pragma unroll
      for (int kt = 1; kt < KTW; ++kt) mm = fmaxf(mm, acc[f][kt][j]);
      m4[f][j] = mm;
    }
#pragma unroll
  for (int off = 1; off < 16; off <<= 1)
#pragma unroll
    for (int f = 0; f < 2; ++f)
#pragma unroll
      for (int j = 0; j < 4; ++j)
        m4[f][j] = fmaxf(m4[f][j], __shfl_xor(m4[f][j], off, 64));

  // ---- wave-segment Newton from tau0 = m_w - 1, ITW fixed iterations,
  // NO barriers (R8 technique): every iterate <= subset root <= tau*,
  // so {x > tau_w} contains the full support for ANY data.
  float tau[2][4];
#pragma unroll
  for (int f = 0; f < 2; ++f)
#pragma unroll
    for (int j = 0; j < 4; ++j) tau[f][j] = m4[f][j] - 1.0f;
  for (int it = 0; it < ITW; ++it) {
    float s1[2][4] = {{0,0,0,0},{0,0,0,0}}, s2[2][4] = {{0,0,0,0},{0,0,0,0}};
#pragma unroll
    for (int kt = 0; kt < KTW; ++kt)
#pragma unroll
      for (int f = 0; f < 2; ++f)
#pragma unroll
        for (int j = 0; j < 4; ++j) {
          float u = fmaxf(acc[f][kt][j] - tau[f][j], 0.f);
          s1[f][j] += u; s2[f][j] = fmaf(u, u, s2[f][j]);
        }
#pragma unroll
    for (int off = 1; off < 16; off <<= 1)
#pragma unroll
      for (int f = 0; f < 2; ++f)
#pragma unroll
        for (int j = 0; j < 4; ++j) {
          s1[f][j] += __shfl_xor(s1[f][j], off, 64);
          s2[f][j] += __shfl_xor(s2[f][j], off, 64);
        }
#pragma unroll
    for (int f = 0; f < 2; ++f)
#pragma unroll
      for (int j = 0; j < 4; ++j)
        tau[f][j] += (s2[f][j] - 1.0f) / (2.0f * s1[f][j]);  // s1>=1 below root
  }

  __syncthreads();   // barrier 1: cnt init visible before any atomic

  // ---- publish per-(row,seg) tau; compact candidates (per-candidate LDS
  // atomics, R5-proven; counts stay TRUE so overflow is detectable).
  if (col == 0) {
#pragma unroll
    for (int f = 0; f < 2; ++f)
#pragma unroll
      for (int j = 0; j < 4; ++j)
        stau[f * 16 + g * 4 + j][wid] = tau[f][j];
  }
#pragma unroll
  for (int kt = 0; kt < KTW; ++kt)
#pragma unroll
    for (int f = 0; f < 2; ++f)
#pragma unroll
      for (int j = 0; j < 4; ++j) {
        float x = acc[f][kt][j];
        if (x > tau[f][j]) {
          const int row = f * 16 + g * 4 + j;
          unsigned int s = atomicAdd(&cnt[row], 1u);
          if (s < CAP) {
            lidx[row][s] = wid * 128 + kt * 16 + col;
            lval[row][s] = x;
          }
        }
      }
  __syncthreads();   // barrier 2 (last): lists + stau complete

  // ---- per-wave epilogue: wave wid owns rows {2*wid, 2*wid+1}; no further
  // barriers (each row's list is touched only by its owning wave).
  for (int rr = 0; rr < 2; ++rr) {
    const int row = wid * 2 + rr;
    const int n = (int)cnt[row];
    int sn = 0;
    float tw;

    if (n <= CAP) {
      // registers <- candidate list
      float xv[5]; int iv[5];                  // 5*64 = CAP
#pragma unroll
      for (int r = 0; r < 5; ++r) {
        const int i = lane + (r << 6);
        if (i < n) { xv[r] = lval[row][i]; iv[r] = lidx[row][i]; }
        else       { xv[r] = -1e30f;       iv[r] = 0; }
      }
      // warm start (R9): tau0 = max over the 16 segment taus (each <= tau*;
      // restricted f == full f on [tau0, inf) since excluded x <= own seg tau).
      float ts = (lane < NW) ? stau[row][lane] : -3e38f;
#pragma unroll
      for (int off = 1; off < 64; off <<= 1) ts = fmaxf(ts, __shfl_xor(ts, off, 64));
      tw = ts;
      for (int it = 0; it < WMAXIT; ++it) {
        float s1 = 0.f, s2 = 0.f;
#pragma unroll
        for (int r = 0; r < 5; ++r) {
          float u = fmaxf(xv[r] - tw, 0.f);
          s1 += u; s2 = fmaf(u, u, s2);
        }
#pragma unroll
        for (int off = 1; off < 64; off <<= 1) {
          s1 += __shfl_xor(s1, off, 64);
          s2 += __shfl_xor(s2, off, 64);
        }
        float step = (s2 - 1.0f) / (2.0f * s1);   // s1 >= 1 below the root
        tw += step;
        if (step < 1e-7f) break;                  // lane-uniform
      }
      // in-place support compaction via ballot-prefix (R10; no atomics).
      // Safe: sources already in regs; dest slot <= source index ordering.
#pragma unroll
      for (int r = 0; r < 5; ++r) {
        const float u = xv[r] - tw;
        const bool pred = (u > 0.f) && (lane + (r << 6) < n);
        const unsigned long long mb = __ballot(pred);
        if (pred) {
          const int slot = sn + __popcll(mb & ((1ull << lane) - 1ull));
          lidx[row][slot] = iv[r]; lval[row][slot] = u * u;
        }
        sn += (int)__popcll(mb);
      }
    } else {
      // ---- overflow repair (rare, exact for ANY data): full fp32 row.
      qsR[wid][lane] = qp[row * D_ + lane] * 0.0625f;
      float xs[32];
      for (int r = 0; r < 32; ++r) {
        const float* krow = kp + (size_t)(lane + (r << 6)) * D_;
        float d = 0.f;
#pragma unroll 4
        for (int dc = 0; dc < D_; dc += 4) {
          float4 kv4 = *(const float4*)(krow + dc);
          d = fmaf(qsR[wid][dc + 0], kv4.x, d);
          d = fmaf(qsR[wid][dc + 1], kv4.y, d);
          d = fmaf(qsR[wid][dc + 2], kv4.z, d);
          d = fmaf(qsR[wid][dc + 3], kv4.w, d);
        }
        xs[r] = d;
      }
      float mx = xs[0];
#pragma unroll
      for (int r = 1; r < 32; ++r) mx = fmaxf(mx, xs[r]);
#pragma unroll
      for (int off = 1; off < 64; off <<= 1) mx = fmaxf(mx, __shfl_xor(mx, off, 64));
      tw = mx - 1.0f;
      for (int it = 0; it < WMAXIT; ++it) {
        float s1 = 0.f, s2 = 0.f;
#pragma unroll
        for (int r = 0; r < 32; ++r) {
          float u = fmaxf(xs[r] - tw, 0.f);
          s1 += u; s2 = fmaf(u, u, s2);
        }
#pragma unroll
        for (int off = 1; off < 64; off <<= 1) {
          s1 += __shfl_xor(s1, off, 64);
          s2 += __shfl_xor(s2, off, 64);
        }
        float step = (s2 - 1.0f) / (2.0f * s1);
        tw += step;
        if (step < 1e-7f) break;
      }
#pragma unroll
      for (int r = 0; r < 32; ++r) {
        const float u = xs[r] - tw;
        const bool pred = u > 0.f;
        const unsigned long long mb = __ballot(pred);
        if (pred) {
          const int slot = sn + __popcll(mb & ((1ull << lane) - 1ull));
          lidx[row][slot] = lane + (r << 6); lval[row][slot] = u * u;
        }
        sn += (int)__popcll(mb);
      }
    }
    if (sn > CAP) sn = CAP;   // p<=1 each, sum=1: support <= CAP in practice

    // ---- parallel PV (R9): entry subgroup eg = lane>>4 strides over the
    // support, d-column d4 = lane&15 (float4); 2-level butterfly; lanes
    // 0-15 write the row.
    const int eg = lane >> 4;
    const int d4 = lane & 15;
    float4 a4 = {0.f, 0.f, 0.f, 0.f};
    for (int i = eg; i < sn; i += 4) {
      const float pv = lval[row][i];
      const float4 vv = *(const float4*)&vp[(size_t)lidx[row][i] * D_ + d4 * 4];
      a4.x = fmaf(pv, vv.x, a4.x); a4.y = fmaf(pv, vv.y, a4.y);
      a4.z = fmaf(pv, vv.z, a4.z); a4.w = fmaf(pv, vv.w, a4.w);
    }
#pragma unroll
    for (int off = 16; off < 64; off <<= 1) {
      a4.x += __shfl_xor(a4.x, off, 64);
      a4.y += __shfl_xor(a4.y, off, 64);
      a4.z += __shfl_xor(a4.z, off, 64);
      a4.w += __shfl_xor(a4.w, off, 64);
    }
    if (lane < 16)
      *(float4*)&op[row * D_ + d4 * 4] = a4;
  }
}

extern "C" void kernel_launch(void* const* d_in, const int* in_sizes, int n_in,
                              void* d_out, int out_size, void* d_ws, size_t ws_size,
                              hipStream_t stream) {
  const float* q = (const float*)d_in[0];
  const float* k = (const float*)d_in[1];
  const float* v = (const float*)d_in[2];
  float* out = (float*)d_out;
  const size_t khi_b = (size_t)KELEMS * 2;   // 4 MB each
  const dim3 grid(BH_ * (S_ / QT));          // 16 * 64 = 1024 blocks

  if (d_ws != nullptr && ws_size >= 2 * khi_b) {
    unsigned short* khi = (unsigned short*)d_ws;
    unsigned short* klo = khi + KELEMS;
    ksplit_kernel<<<dim3(KELEMS / (256 * 4)), dim3(256), 0, stream>>>(k, khi, klo);
    entmax_attn_kernel<true><<<grid, dim3(BLOCK), 0, stream>>>(q, k, khi, klo, v, out);
  } else {
    entmax_attn_kernel<false><<<grid, dim3(BLOCK), 0, stream>>>(q, k, nullptr, nullptr, v, out);
  }
}

// Round 12
// 289.239 us; speedup vs baseline: 3.0673x; 1.0031x over previous
//
#include <hip/hip_runtime.h>
#include <math.h>

// Problem constants (B=2, H=8, S=2048, D=64)
#define BH_    16
#define S_     2048
#define D_     64
#define KELEMS (BH_ * S_ * D_)   // 2,097,152 K elements
#define NROWS  (BH_ * S_)        // 32,768 query rows
#define QT     32                // queries per block (2 MFMA A-frags per wave)
#define BLOCK  1024              // 16 waves
#define NW     16
#define KTW    8                 // 16x16 C-tiles per wave: 128 keys/wave
#define CAP    320               // per-row candidate cap (R9: avg ~126/row at
                                 // 5-iter segment tau; overflow -> repair kernel)
#define ITW    5                 // wave-segment Newton iterations (fixed)
#define WMAXIT 24                // exact row Newton max iters (early-exit)
#define SUPR   256               // repair-kernel support cap

typedef __attribute__((ext_vector_type(8))) short bf16x8;   // 8 bf16 = 4 VGPR
typedef __attribute__((ext_vector_type(4))) float f32x4;

// Exact hi/lo bf16 truncation split of 8 consecutive floats.
// x = hi + lo + eps, |eps| <= 2^-15 |x|; products use hh + hl + lh (drop ll).
__device__ __forceinline__ void split8(const float4 f0, const float4 f1,
                                       bf16x8& hi, bf16x8& lo) {
  union { bf16x8 v; unsigned int u[4]; } H, L;
  const float ff[8] = {f0.x, f0.y, f0.z, f0.w, f1.x, f1.y, f1.z, f1.w};
#pragma unroll
  for (int p = 0; p < 4; ++p) {
    unsigned int b0 = __float_as_uint(ff[2 * p]);
    unsigned int b1 = __float_as_uint(ff[2 * p + 1]);
    unsigned int h0 = b0 & 0xFFFF0000u;
    unsigned int h1 = b1 & 0xFFFF0000u;
    H.u[p] = (h0 >> 16) | h1;                       // lo short = elem 2p
    float l0 = ff[2 * p]     - __uint_as_float(h0); // exact in fp32
    float l1 = ff[2 * p + 1] - __uint_as_float(h1);
    L.u[p] = (__float_as_uint(l0) >> 16) | (__float_as_uint(l1) & 0xFFFF0000u);
  }
  hi = H.v; lo = L.v;
}

// Prepass: K fp32 -> (Khi, Klo) bf16, same element order; zero overflow flags.
__global__ __launch_bounds__(256)
void ksplit_kernel(const float* __restrict__ k,
                   unsigned short* __restrict__ khi,
                   unsigned short* __restrict__ klo,
                   int* __restrict__ gflag) {
  const int gi = blockIdx.x * 256 + threadIdx.x;
  if (gflag != nullptr && gi < NROWS) gflag[gi] = 0;
  const int i = gi * 4;
  float4 x = *(const float4*)(k + i);
  ushort4 h, l;
  {
    unsigned int b;
    b = __float_as_uint(x.x); h.x = (unsigned short)(b >> 16);
    l.x = (unsigned short)(__float_as_uint(x.x - __uint_as_float(b & 0xFFFF0000u)) >> 16);
    b = __float_as_uint(x.y); h.y = (unsigned short)(b >> 16);
    l.y = (unsigned short)(__float_as_uint(x.y - __uint_as_float(b & 0xFFFF0000u)) >> 16);
    b = __float_as_uint(x.z); h.z = (unsigned short)(b >> 16);
    l.z = (unsigned short)(__float_as_uint(x.z - __uint_as_float(b & 0xFFFF0000u)) >> 16);
    b = __float_as_uint(x.w); h.w = (unsigned short)(b >> 16);
    l.w = (unsigned short)(__float_as_uint(x.w - __uint_as_float(b & 0xFFFF0000u)) >> 16);
  }
  *(ushort4*)(khi + i) = h;
  *(ushort4*)(klo + i) = l;
}

// ============ Main kernel: R11 minus the in-kernel repair path ============
// R11 lesson: the rarely-taken overflow branch (xs[32]+qsR) inflated the
// epilogue's static register demand past the 128-reg budget (acc holds 64),
// causing ~116 MB/dispatch of scratch spill (WRITE_SIZE 124 MB vs out 8.4).
// Now overflow rows (n > CAP, rare) just set gflag and skip; a follow-up
// repair kernel with its own register budget recomputes them exactly.
template <bool PRE>
__global__ __launch_bounds__(BLOCK, 4)   // acc=64 AGPR -> 4 waves/SIMD
void entmax_attn_kernel(const float* __restrict__ q,
                        const float* __restrict__ k,
                        const unsigned short* __restrict__ khi,
                        const unsigned short* __restrict__ klo,
                        const float* __restrict__ v,
                        int* __restrict__ gflag,
                        float* __restrict__ out) {
  __shared__ unsigned int cnt[QT];     // TRUE candidate counts (un-clamped)
  __shared__ float stau[QT][NW];       // per-(row, segment) Newton-5 tau
  __shared__ int   lidx[QT][CAP];      // candidates: key index  (40 KB)
  __shared__ float lval[QT][CAP];      // candidates: x, then p  (40 KB)

  const int t    = threadIdx.x;
  const int wid  = t >> 6;             // 0..15 (= key segment)
  const int lane = t & 63;
  const int g    = lane >> 4;          // lane group 0..3
  const int col  = lane & 15;          // MFMA col (key) / A-row index

  // head-XCD affinity: bh = blk & 15 -> blk % 8 == bh % 8 under round-robin.
  const int blk = blockIdx.x;
  const int bh  = blk & 15;
  const int qt  = blk >> 4;            // 0..63
  const float* qp = q + ((size_t)bh * S_ + (size_t)qt * QT) * D_;
  const float* kp = k + (size_t)bh * S_ * D_;
  const float* vp = v + (size_t)bh * S_ * D_;
  float* op = out + ((size_t)bh * S_ + (size_t)qt * QT) * D_;

  if (t < QT) cnt[t] = 0;

  // ---- Q fragments: A-frag f covers rows f*16..f*16+15 (row = col).
  // Fold scale (1/8) and entmax /2 => *1/16 (power of 2: exact prescale).
  bf16x8 qh[2][2], ql[2][2];
#pragma unroll
  for (int f = 0; f < 2; ++f)
#pragma unroll
    for (int ks = 0; ks < 2; ++ks) {
      const float* src = qp + (f * 16 + col) * D_ + ks * 32 + g * 8;
      float4 f0 = *(const float4*)src;
      float4 f1 = *(const float4*)(src + 4);
      f0.x *= 0.0625f; f0.y *= 0.0625f; f0.z *= 0.0625f; f0.w *= 0.0625f;
      f1.x *= 0.0625f; f1.y *= 0.0625f; f1.z *= 0.0625f; f1.w *= 0.0625f;
      split8(f0, f1, qh[f][ks], ql[f][ks]);
    }

  // ---- QK^T: acc[f][kt][j] = x[row=f*16+g*4+j][key=wid*128+kt*16+col].
  // fp32-ish accuracy: qh*kh + qh*kl + ql*kh (drop ll, ~2^-15 rel).
  f32x4 acc[2][KTW];
#pragma unroll
  for (int f = 0; f < 2; ++f)
#pragma unroll
    for (int kt = 0; kt < KTW; ++kt) acc[f][kt] = (f32x4){0.f, 0.f, 0.f, 0.f};
#pragma unroll
  for (int kt = 0; kt < KTW; ++kt) {
    const size_t rowoff = (size_t)(wid * 128 + kt * 16 + col) * D_;
#pragma unroll
    for (int ks = 0; ks < 2; ++ks) {
      bf16x8 kh, kl;
      if (PRE) {
        const size_t eoff = (size_t)bh * S_ * D_ + rowoff + ks * 32 + g * 8;
        kh = *(const bf16x8*)(khi + eoff);
        kl = *(const bf16x8*)(klo + eoff);
      } else {
        const float* src = kp + rowoff + ks * 32 + g * 8;
        split8(*(const float4*)src, *(const float4*)(src + 4), kh, kl);
      }
#pragma unroll
      for (int f = 0; f < 2; ++f) {
        acc[f][kt] = __builtin_amdgcn_mfma_f32_16x16x32_bf16(qh[f][ks], kh, acc[f][kt], 0, 0, 0);
        acc[f][kt] = __builtin_amdgcn_mfma_f32_16x16x32_bf16(qh[f][ks], kl, acc[f][kt], 0, 0, 0);
        acc[f][kt] = __builtin_amdgcn_mfma_f32_16x16x32_bf16(ql[f][ks], kh, acc[f][kt], 0, 0, 0);
      }
    }
  }

  // ---- wave-segment row max over this wave's 128 keys (16-lane butterfly).
  float m4[2][4];
#pragma unroll
  for (int f = 0; f < 2; ++f)
#pragma unroll
    for (int j = 0; j < 4; ++j) {
      float mm = acc[f][0][j];
#pragma unroll
      for (int kt = 1; kt < KTW; ++kt) mm = fmaxf(mm, acc[f][kt][j]);
      m4[f][j] = mm;
    }
#pragma unroll
  for (int off = 1; off < 16; off <<= 1)
#pragma unroll
    for (int f = 0; f < 2; ++f)
#pragma unroll
      for (int j = 0; j < 4; ++j)
        m4[f][j] = fmaxf(m4[f][j], __shfl_xor(m4[f][j], off, 64));

  // ---- wave-segment Newton from tau0 = m_w - 1, ITW fixed iterations,
  // NO barriers: every iterate <= subset root <= tau*, so {x > tau_w}
  // contains the full support for ANY data.
  float tau[2][4];
#pragma unroll
  for (int f = 0; f < 2; ++f)
#pragma unroll
    for (int j = 0; j < 4; ++j) tau[f][j] = m4[f][j] - 1.0f;
  for (int it = 0; it < ITW; ++it) {
    float s1[2][4] = {{0,0,0,0},{0,0,0,0}}, s2[2][4] = {{0,0,0,0},{0,0,0,0}};
#pragma unroll
    for (int kt = 0; kt < KTW; ++kt)
#pragma unroll
      for (int f = 0; f < 2; ++f)
#pragma unroll
        for (int j = 0; j < 4; ++j) {
          float u = fmaxf(acc[f][kt][j] - tau[f][j], 0.f);
          s1[f][j] += u; s2[f][j] = fmaf(u, u, s2[f][j]);
        }
#pragma unroll
    for (int off = 1; off < 16; off <<= 1)
#pragma unroll
      for (int f = 0; f < 2; ++f)
#pragma unroll
        for (int j = 0; j < 4; ++j) {
          s1[f][j] += __shfl_xor(s1[f][j], off, 64);
          s2[f][j] += __shfl_xor(s2[f][j], off, 64);
        }
#pragma unroll
    for (int f = 0; f < 2; ++f)
#pragma unroll
      for (int j = 0; j < 4; ++j)
        tau[f][j] += (s2[f][j] - 1.0f) / (2.0f * s1[f][j]);  // s1>=1 below root
  }

  __syncthreads();   // barrier 1: cnt init visible before any atomic

  // ---- publish per-(row,seg) tau; compact candidates (per-candidate LDS
  // atomics; counts stay TRUE so overflow is detectable).
  if (col == 0) {
#pragma unroll
    for (int f = 0; f < 2; ++f)
#pragma unroll
      for (int j = 0; j < 4; ++j)
        stau[f * 16 + g * 4 + j][wid] = tau[f][j];
  }
#pragma unroll
  for (int kt = 0; kt < KTW; ++kt)
#pragma unroll
    for (int f = 0; f < 2; ++f)
#pragma unroll
      for (int j = 0; j < 4; ++j) {
        float x = acc[f][kt][j];
        if (x > tau[f][j]) {
          const int row = f * 16 + g * 4 + j;
          unsigned int s = atomicAdd(&cnt[row], 1u);
          if (s < CAP) {
            lidx[row][s] = wid * 128 + kt * 16 + col;
            lval[row][s] = x;
          }
        }
      }
  __syncthreads();   // barrier 2 (last): lists + stau complete

  // ---- per-wave epilogue: wave wid owns rows {2*wid, 2*wid+1}.
  for (int rr = 0; rr < 2; ++rr) {
    const int row = wid * 2 + rr;
    int n = (int)cnt[row];
    if (PRE) {
      if (n > CAP) {                      // rare: defer to repair kernel
        if (lane == 0) gflag[(size_t)bh * S_ + qt * QT + row] = 1;
        continue;
      }
    } else {
      if (n > CAP) n = CAP;               // no-ws fallback: clamp (R5 behavior)
    }

    // registers <- candidate list
    float xv[5]; int iv[5];               // 5*64 = CAP
#pragma unroll
    for (int r = 0; r < 5; ++r) {
      const int i = lane + (r << 6);
      if (i < n) { xv[r] = lval[row][i]; iv[r] = lidx[row][i]; }
      else       { xv[r] = -1e30f;       iv[r] = 0; }
    }
    // warm start: tau0 = max over the 16 segment taus (each <= tau*;
    // restricted f == full f on [tau0, inf) since excluded x <= own seg tau).
    float ts = (lane < NW) ? stau[row][lane] : -3e38f;
#pragma unroll
    for (int off = 1; off < 64; off <<= 1) ts = fmaxf(ts, __shfl_xor(ts, off, 64));
    float tw = ts;
    for (int it = 0; it < WMAXIT; ++it) {
      float s1 = 0.f, s2 = 0.f;
#pragma unroll
      for (int r = 0; r < 5; ++r) {
        float u = fmaxf(xv[r] - tw, 0.f);
        s1 += u; s2 = fmaf(u, u, s2);
      }
#pragma unroll
      for (int off = 1; off < 64; off <<= 1) {
        s1 += __shfl_xor(s1, off, 64);
        s2 += __shfl_xor(s2, off, 64);
      }
      float step = (s2 - 1.0f) / (2.0f * s1);   // s1 >= 1 below the root
      tw += step;
      if (step < 1e-7f) break;                  // lane-uniform
    }
    // in-place support compaction via ballot-prefix (no atomics).
    int sn = 0;
#pragma unroll
    for (int r = 0; r < 5; ++r) {
      const float u = xv[r] - tw;
      const bool pred = (u > 0.f) && (lane + (r << 6) < n);
      const unsigned long long mb = __ballot(pred);
      if (pred) {
        const int slot = sn + __popcll(mb & ((1ull << lane) - 1ull));
        lidx[row][slot] = iv[r]; lval[row][slot] = u * u;
      }
      sn += (int)__popcll(mb);
    }

    // ---- parallel PV: entry subgroup eg = lane>>4 strides over the support,
    // d-column d4 = lane&15 (float4); 2-level butterfly; lanes 0-15 write.
    const int eg = lane >> 4;
    const int d4 = lane & 15;
    float4 a4 = {0.f, 0.f, 0.f, 0.f};
    for (int i = eg; i < sn; i += 4) {
      const float pv = lval[row][i];
      const float4 vv = *(const float4*)&vp[(size_t)lidx[row][i] * D_ + d4 * 4];
      a4.x = fmaf(pv, vv.x, a4.x); a4.y = fmaf(pv, vv.y, a4.y);
      a4.z = fmaf(pv, vv.z, a4.z); a4.w = fmaf(pv, vv.w, a4.w);
    }
#pragma unroll
    for (int off = 16; off < 64; off <<= 1) {
      a4.x += __shfl_xor(a4.x, off, 64);
      a4.y += __shfl_xor(a4.y, off, 64);
      a4.z += __shfl_xor(a4.z, off, 64);
      a4.w += __shfl_xor(a4.w, off, 64);
    }
    if (lane < 16)
      *(float4*)&op[row * D_ + d4 * 4] = a4;
  }
}

// ============ Repair kernel: exact recompute of flagged rows ============
// Own register budget (xs[32] spills nothing here). Grid-strided waves scan
// the 32K flags (~3us when clean); flagged rows get full fp32 QK^T, exact
// Newton, and sparse PV. Stream order puts this after the main kernel.
__global__ __launch_bounds__(256)
void entmax_repair_kernel(const float* __restrict__ q,
                          const float* __restrict__ k,
                          const float* __restrict__ v,
                          const int* __restrict__ gflag,
                          float* __restrict__ out) {
  __shared__ float qs[4][D_];
  __shared__ int   sidx[4][SUPR];
  __shared__ float sp[4][SUPR];

  const int wid  = threadIdx.x >> 6;
  const int lane = threadIdx.x & 63;
  const int gw   = blockIdx.x * 4 + wid;       // global wave id
  const int nw   = gridDim.x * 4;

  for (int rowg = gw; rowg < NROWS; rowg += nw) {
    if (gflag[rowg] == 0) continue;
    const int bh = rowg >> 11;                 // rowg / S_
    const float* kb = k + (size_t)bh * S_ * D_;
    const float* vb = v + (size_t)bh * S_ * D_;

    qs[wid][lane] = q[(size_t)rowg * D_ + lane] * 0.0625f;  // same-wave: in-order
    float xs[32];
    for (int r = 0; r < 32; ++r) {
      const float* krow = kb + (size_t)(lane + (r << 6)) * D_;
      float d = 0.f;
#pragma unroll 4
      for (int dc = 0; dc < D_; dc += 4) {
        float4 kv4 = *(const float4*)(krow + dc);
        d = fmaf(qs[wid][dc + 0], kv4.x, d);
        d = fmaf(qs[wid][dc + 1], kv4.y, d);
        d = fmaf(qs[wid][dc + 2], kv4.z, d);
        d = fmaf(qs[wid][dc + 3], kv4.w, d);
      }
      xs[r] = d;
    }
    float mx = xs[0];
#pragma unroll
    for (int r = 1; r < 32; ++r) mx = fmaxf(mx, xs[r]);
#pragma unroll
    for (int off = 1; off < 64; off <<= 1) mx = fmaxf(mx, __shfl_xor(mx, off, 64));
    float tau = mx - 1.0f;
    for (int it = 0; it < 32; ++it) {
      float s1 = 0.f, s2 = 0.f;
#pragma unroll
      for (int r = 0; r < 32; ++r) {
        float u = fmaxf(xs[r] - tau, 0.f);
        s1 += u; s2 = fmaf(u, u, s2);
      }
#pragma unroll
      for (int off = 1; off < 64; off <<= 1) {
        s1 += __shfl_xor(s1, off, 64);
        s2 += __shfl_xor(s2, off, 64);
      }
      float step = (s2 - 1.0f) / (2.0f * s1);
      tau += step;
      if (step < 1e-7f) break;
    }
    int sn = 0;
#pragma unroll
    for (int r = 0; r < 32; ++r) {
      const float u = xs[r] - tau;
      const bool pred = u > 0.f;
      const unsigned long long mb = __ballot(pred);
      if (pred) {
        const int slot = sn + __popcll(mb & ((1ull << lane) - 1ull));
        if (slot < SUPR) { sidx[wid][slot] = lane + (r << 6); sp[wid][slot] = u * u; }
      }
      sn += (int)__popcll(mb);
    }
    if (sn > SUPR) sn = SUPR;
    float s = 0.f;
    for (int i = 0; i < sn; ++i)
      s = fmaf(sp[wid][i], vb[(size_t)sidx[wid][i] * D_ + lane], s);
    out[(size_t)rowg * D_ + lane] = s;
  }
}

extern "C" void kernel_launch(void* const* d_in, const int* in_sizes, int n_in,
                              void* d_out, int out_size, void* d_ws, size_t ws_size,
                              hipStream_t stream) {
  const float* q = (const float*)d_in[0];
  const float* k = (const float*)d_in[1];
  const float* v = (const float*)d_in[2];
  float* out = (float*)d_out;
  const size_t khi_b  = (size_t)KELEMS * 2;    // 4 MB each
  const size_t flag_b = (size_t)NROWS * 4;     // 128 KB
  const dim3 grid(BH_ * (S_ / QT));            // 16 * 64 = 1024 blocks

  if (d_ws != nullptr && ws_size >= 2 * khi_b + flag_b) {
    unsigned short* khi = (unsigned short*)d_ws;
    unsigned short* klo = khi + KELEMS;
    int* gflag = (int*)((char*)d_ws + 2 * khi_b);
    ksplit_kernel<<<dim3(KELEMS / (256 * 4)), dim3(256), 0, stream>>>(k, khi, klo, gflag);
    entmax_attn_kernel<true><<<grid, dim3(BLOCK), 0, stream>>>(
        q, k, khi, klo, v, gflag, out);
    entmax_repair_kernel<<<dim3(256), dim3(256), 0, stream>>>(q, k, v, gflag, out);
  } else {
    entmax_attn_kernel<false><<<grid, dim3(BLOCK), 0, stream>>>(
        q, k, nullptr, nullptr, v, nullptr, out);
  }
}